// Round 12
// baseline (424.278 us; speedup 1.0000x reference)
//
#include <hip/hip_runtime.h>
#include <hip/hip_bf16.h>

// B=8, S=2048, D=1024, O=1024
// qp=q@Wq, kp=k@Wk, vp=k@Wv ; attn=qp@kp^T (no scale); w=softmax(attn,-1)
// context = attn_w^T @ vp ; out = concat([q, context], -1)  fp32 [B,S,2048]
//
// All GEMMs plain fp16 in / fp32 MFMA accumulate. attnT = kp @ qp^T computed
// transposed; epilogue writes f16 e=exp(l-M_blk) + per-64-row partials;
// merge -> scale table; in-place rescale; PV.
//
// GEMM r12: 128x128 tile, BK=64, 4 waves (2Mx2N), 32x32x16 f16 MFMA,
// 2 phases/K-tile (8 MFMA + 8 ds_read_b128 + 2 stage-issues each),
// counted vmcnt(4), setprio, XCD swizzle, conflict-free swizzled LDS.
// LDS 64 KiB (2x32KiB buffers) -> 2 blocks/CU co-resident: independent
// (non-barrier-synced) waves fill the MFMA pipe during the other block's
// barrier/waitcnt stalls (m97/m114 mechanism; r8-r11 showed the 256²
// 1-block/CU structure is stall-bound at ~30% regardless of schedule).
// VGPR ~150 fits __launch_bounds__(256,2) without spill (r9 lesson: never
// cap below the 64-VGPR accumulator + frags footprint).

typedef __attribute__((ext_vector_type(4))) float f32x4;
typedef __attribute__((ext_vector_type(16))) float f32x16;
typedef _Float16 f16;
typedef __attribute__((ext_vector_type(8))) _Float16 f16x8;
typedef __attribute__((ext_vector_type(4))) _Float16 f16x4;

#define LOG2E 1.4426950408889634f

#define CM_F32     0
#define CM_F16     1
#define CM_F16T    3
#define CM_ATTN    4
#define CM_PROJ3   5

// Stage one 8 KiB unit (WHICH: 0=A,1=B; KS: k-half) of K-tile KT into buffer
// at byte offset BO. LDS dst linear in tid; XOR swizzle applied by
// pre-swizzling the GLOBAL source k-chunk (both-sides-or-neither).
// 256 thr x 16B = 4 KiB/pass; rows 0..63 then 64..127.
#define STAGE(WHICH, KS, KT, BO) do { \
    const char* _gb = (WHICH) ? Bb : Ab; \
    const int _ld = (WHICH) ? ldb : lda; \
    const long _r = (WHICH) ? (long)(bn + srow0) : (long)(bm + srow0); \
    const int _k0 = (KT) * 64 + (KS) * 32 + sh8; \
    char* _dst = (char*)smem + (BO) + (WHICH) * 16384 + (KS) * 8192 + wave * 1024; \
    const char* _g0 = _gb + ((_r * _ld + _k0) << 1); \
    const char* _g1 = _gb + (((_r + 64) * _ld + _k0) << 1); \
    __builtin_amdgcn_global_load_lds((const __attribute__((address_space(1))) void*)_g0, \
        (__attribute__((address_space(3))) void*)_dst, 16, 0, 0); \
    __builtin_amdgcn_global_load_lds((const __attribute__((address_space(1))) void*)_g1, \
        (__attribute__((address_space(3))) void*)(_dst + 4096), 16, 0, 0); \
} while (0)

// One phase: K-half KS, BOTH k-steps. 8 ds_read_b128 -> stage issue ->
// barrier -> (compiler lgkmcnt) -> 8 MFMA 32x32x16 -> counted vmcnt ->
// barrier.
#define GPHASE2(KS, STAGE_CODE, VM) do { \
    f16x8 af[2][2], bb[2][2]; \
    _Pragma("unroll") \
    for (int s = 0; s < 2; ++s) { \
        _Pragma("unroll") \
        for (int mt = 0; mt < 2; ++mt) \
            af[s][mt] = *(const f16x8*)(smem + \
                ((bufo + (KS) * 8192 + abase[mt]) ^ (s << 5))); \
        _Pragma("unroll") \
        for (int nt = 0; nt < 2; ++nt) \
            bb[s][nt] = *(const f16x8*)(smem + \
                ((bufo + (KS) * 8192 + bbase[nt]) ^ (s << 5))); \
    } \
    STAGE_CODE; \
    __builtin_amdgcn_s_barrier(); \
    __builtin_amdgcn_s_setprio(1); \
    _Pragma("unroll") \
    for (int s = 0; s < 2; ++s) \
        _Pragma("unroll") \
        for (int mt = 0; mt < 2; ++mt) \
            _Pragma("unroll") \
            for (int nt = 0; nt < 2; ++nt) \
                acc[mt][nt] = __builtin_amdgcn_mfma_f32_32x32x16_f16( \
                    af[s][mt], bb[s][nt], acc[mt][nt], 0, 0, 0); \
    __builtin_amdgcn_s_setprio(0); \
    VM; \
    __builtin_amdgcn_s_barrier(); \
} while (0)

// CM_PROJ3: blockIdx.y selects {q@Wq->qp(F16), k@Wk->kp(F16),
// k@Wv->vpT(F16T via pm, stride M)}. A trio: y>=1 uses A+M*1024 (kpack
// contiguous after qpack); B trio contiguous (1 MiB elems apart).
template<int CMODE>
__global__ __launch_bounds__(256, 2)
void gemm128(const f16* __restrict__ A, const f16* __restrict__ B,
             void* __restrict__ Cv,
             int M, int N, int K, int lda, int ldb, int ldc,
             long az, long bz, long cz,
             float* __restrict__ pm, float* __restrict__ ps)
{
    __shared__ __align__(16) char smem[65536];

    const int z = blockIdx.z;
    const char* Ab;
    const char* Bb;
    if (CMODE == CM_PROJ3) {
        const int y = blockIdx.y;
        Ab = (const char*)(A + (y ? (long)M * 1024 : 0));
        Bb = (const char*)(B + (long)y * 1024 * 1024);
    } else {
        Ab = (const char*)(A + z * az);
        Bb = (const char*)(B + z * bz);
    }

    // XCD-aware swizzle (all launches have nwg % 8 == 0)
    const int nbx = N >> 7;
    int wg = blockIdx.x;
    const int nwg = gridDim.x;
    if ((nwg & 7) == 0) wg = (wg & 7) * (nwg >> 3) + (wg >> 3);
    const int bm = (wg / nbx) << 7;
    const int bn = (wg % nbx) << 7;

    const int tid = threadIdx.x;
    const int wave = tid >> 6;      // 0..3
    const int lane = tid & 63;
    const int l31 = lane & 31;
    const int h5 = lane >> 5;
    const int wm = wave >> 1;       // 0..1 -> rows wm*64..+64
    const int wn = wave & 1;        // 0..1 -> cols wn*64..+64

    // swizzled slot: slot = (2*s ^ h5 ^ f) with f = (row ^ row>>2)&3
    const int f3 = (l31 ^ (l31 >> 2)) & 3;
    const int sl = ((h5 ^ f3) << 4);
    int abase[2], bbase[2];
    #pragma unroll
    for (int mt = 0; mt < 2; ++mt)
        abase[mt] = (wm * 64 + mt * 32 + l31) * 64 + sl;
    #pragma unroll
    for (int nt = 0; nt < 2; ++nt)
        bbase[nt] = 16384 + (wn * 64 + nt * 32 + l31) * 64 + sl;

    // staging per-thread constants
    const int srow0 = tid >> 2;                                // 0..63
    const int sh8 = ((tid ^ (tid >> 2) ^ (tid >> 4)) & 3) * 8;

    f32x16 acc[2][2];
    #pragma unroll
    for (int mt = 0; mt < 2; ++mt)
        #pragma unroll
        for (int nt = 0; nt < 2; ++nt)
            acc[mt][nt] = (f32x16)(0.f);

    const int nt_k = K >> 6;

    {
        const int t1p = (nt_k > 1) ? 1 : 0;
        STAGE(0, 0, 0, 0);
        STAGE(1, 0, 0, 0);
        STAGE(0, 1, 0, 0);
        STAGE(1, 1, 0, 0);
        STAGE(0, 0, t1p, 32768);
        STAGE(1, 0, t1p, 32768);
        asm volatile("s_waitcnt vmcnt(4)" ::: "memory");
        __builtin_amdgcn_s_barrier();
    }

    for (int t = 0; t < nt_k; ++t) {
        const int bufo = (t & 1) << 15;
        const int nbo = bufo ^ 32768;
        const int t1 = (t + 1 < nt_k) ? t + 1 : nt_k - 1;
        const int t2 = (t + 2 < nt_k) ? t + 2 : nt_k - 1;
        // phase 1: compute KS0; stage t1.KS1 -> other buffer.
        GPHASE2(0, { STAGE(0, 1, t1, nbo); STAGE(1, 1, t1, nbo); }, );
        // phase 2: compute KS1; stage t2.KS0 -> current buffer (KS0 reads
        // retired at phase-1 barrier). vmcnt(4) retires t1.KS0+KS1 (read
        // next iter), leaves t2.KS0's 4 loads in flight.
        GPHASE2(1, { STAGE(0, 0, t2, bufo); STAGE(1, 0, t2, bufo); },
                asm volatile("s_waitcnt vmcnt(4)" ::: "memory"));
    }
    // drain pending LDS-DMA before the workgroup can exit
    asm volatile("s_waitcnt vmcnt(0)" ::: "memory");

    // ---- epilogue: 32x32 D mapping col=lane&31, row=(reg&3)+4*(lane>>5)+8*(reg>>2)
    if (CMODE == CM_ATTN) {
        f16* E = (f16*)Cv + z * cz;
        #pragma unroll
        for (int nt = 0; nt < 2; ++nt) {
            float Mx = -3.4e38f;
            #pragma unroll
            for (int mt = 0; mt < 2; ++mt)
                #pragma unroll
                for (int r = 0; r < 16; ++r)
                    Mx = fmaxf(Mx, acc[mt][nt][r]);
            Mx = fmaxf(Mx, __shfl_xor(Mx, 32, 64));
            float Sm = 0.f;
            #pragma unroll
            for (int mt = 0; mt < 2; ++mt)
                #pragma unroll
                for (int r = 0; r < 16; ++r) {
                    const float e = exp2f((acc[mt][nt][r] - Mx) * LOG2E);
                    acc[mt][nt][r] = e;
                    Sm += e;
                }
            Sm += __shfl_xor(Sm, 32, 64);
            const int col = bn + wn * 64 + nt * 32 + l31;
            #pragma unroll
            for (int mt = 0; mt < 2; ++mt) {
                const int row0 = bm + wm * 64 + mt * 32 + h5 * 4;
                #pragma unroll
                for (int rq = 0; rq < 4; ++rq)
                    #pragma unroll
                    for (int rr = 0; rr < 4; ++rr)
                        E[(long)(row0 + rq * 8 + rr) * ldc + col] =
                            (f16)acc[mt][nt][rq * 4 + rr];
            }
            if (lane < 32) {
                // per-64-row-block partials: block idx = (bm>>6)+wm in [0,32)
                const long pidx = ((long)z * 32 + (bm >> 6) + wm) * N + col;
                pm[pidx] = Mx * LOG2E;   // log2 domain
                ps[pidx] = Sm;
            }
        }
        return;
    }

    #pragma unroll
    for (int mt = 0; mt < 2; ++mt) {
        #pragma unroll
        for (int nt = 0; nt < 2; ++nt) {
            const int row0 = bm + wm * 64 + mt * 32 + h5 * 4;
            const int col = bn + wn * 64 + nt * 32 + l31;
            if (CMODE == CM_F32) {
                float* C = (float*)Cv + z * cz;
                #pragma unroll
                for (int rq = 0; rq < 4; ++rq)
                    #pragma unroll
                    for (int rr = 0; rr < 4; ++rr)
                        C[(long)(row0 + rq * 8 + rr) * ldc + col] =
                            acc[mt][nt][rq * 4 + rr];
            } else if (CMODE == CM_F16) {
                f16* C = (f16*)Cv + z * cz;
                #pragma unroll
                for (int rq = 0; rq < 4; ++rq)
                    #pragma unroll
                    for (int rr = 0; rr < 4; ++rr)
                        C[(long)(row0 + rq * 8 + rr) * ldc + col] =
                            (f16)acc[mt][nt][rq * 4 + rr];
            } else if (CMODE == CM_F16T) { // C^T[col][rows]
                f16* C = (f16*)Cv + z * cz;
                #pragma unroll
                for (int rq = 0; rq < 4; ++rq) {
                    f16x4 v;
                    #pragma unroll
                    for (int rr = 0; rr < 4; ++rr) v[rr] = (f16)acc[mt][nt][rq * 4 + rr];
                    *(f16x4*)(C + (long)col * ldc + row0 + rq * 8) = v;
                }
            } else { // CM_PROJ3
                const int y = blockIdx.y;
                if (y < 2) {
                    f16* C = (f16*)Cv + (long)y * M * 1024;
                    #pragma unroll
                    for (int rq = 0; rq < 4; ++rq)
                        #pragma unroll
                        for (int rr = 0; rr < 4; ++rr)
                            C[(long)(row0 + rq * 8 + rr) * 1024 + col] =
                                (f16)acc[mt][nt][rq * 4 + rr];
                } else {
                    f16* C = (f16*)pm;   // vpT [1024][M]
                    #pragma unroll
                    for (int rq = 0; rq < 4; ++rq) {
                        f16x4 v;
                        #pragma unroll
                        for (int rr = 0; rr < 4; ++rr)
                            v[rr] = (f16)acc[mt][nt][rq * 4 + rr];
                        *(f16x4*)(C + (long)col * M + row0 + rq * 8) = v;
                    }
                }
            }
        }
    }
}

// ---------------------------------------------------------------------------
// q rows: fp32 [R,1024] -> f16 [R,1024] cast AND fp32 copy into out[:,0:1024]
// ---------------------------------------------------------------------------
__global__ __launch_bounds__(256)
void pack_cast_q(const float* __restrict__ in, f16* __restrict__ op,
                 float* __restrict__ oq, long nquads)
{
    const long i = (long)blockIdx.x * 256 + threadIdx.x;
    if (i >= nquads) return;
    const long row = i >> 8;
    const int c = (int)(i & 255) * 4;
    const float4 v = *(const float4*)(in + row * 1024 + c);
    *(float4*)(oq + row * 2048 + c) = v;
    f16x4 h;
    h[0] = (f16)v.x; h[1] = (f16)v.y; h[2] = (f16)v.z; h[3] = (f16)v.w;
    *(f16x4*)(op + row * 1024 + c) = h;
}

__global__ __launch_bounds__(256)
void pack_cast_k(const float* __restrict__ in, f16* __restrict__ op, long nquads)
{
    const long i = (long)blockIdx.x * 256 + threadIdx.x;
    if (i >= nquads) return;
    const long row = i >> 8;
    const int c = (int)(i & 255) * 4;
    const float4 v = *(const float4*)(in + row * 1024 + c);
    f16x4 h;
    h[0] = (f16)v.x; h[1] = (f16)v.y; h[2] = (f16)v.z; h[3] = (f16)v.w;
    *(f16x4*)(op + row * 1024 + c) = h;
}

// ---------------------------------------------------------------------------
// W [1024 d][1024 o] fp32 -> Wt [1024 o][1024 d] f16 (transpose + cast)
// ---------------------------------------------------------------------------
__global__ __launch_bounds__(256)
void pack_W_T(const float* __restrict__ W, f16* __restrict__ Wt)
{
    __shared__ float tile[64][65];
    const int d0 = blockIdx.y * 64, o0 = blockIdx.x * 64;
    const int t = threadIdx.x;
    const int rr = t >> 4, c4 = (t & 15) * 4;
    #pragma unroll
    for (int it = 0; it < 4; ++it) {
        const int r = rr + it * 16;
        const float4 v = *(const float4*)(W + (long)(d0 + r) * 1024 + o0 + c4);
        tile[r][c4] = v.x; tile[r][c4 + 1] = v.y;
        tile[r][c4 + 2] = v.z; tile[r][c4 + 3] = v.w;
    }
    __syncthreads();
    #pragma unroll
    for (int it = 0; it < 4; ++it) {
        const int orow = rr + it * 16;
        f16x4 h;
        #pragma unroll
        for (int j = 0; j < 4; ++j) h[j] = (f16)tile[c4 + j][orow];
        *(f16x4*)(Wt + (long)(o0 + orow) * 1024 + d0 + c4) = h;
    }
}

// ---------------------------------------------------------------------------
// merge 32 per-block partials -> scale[z][32][2048] = exp2(pm - L)
// ---------------------------------------------------------------------------
__global__ __launch_bounds__(256)
void softmax_merge32(const float* __restrict__ pm, const float* __restrict__ ps,
                     float* __restrict__ scale, int nq)
{
    const int idx = blockIdx.x * 256 + threadIdx.x;
    if (idx >= nq) return;
    const int z = idx >> 11, q = idx & 2047;
    const float* pmz = pm + ((long)z * 32) * 2048 + q;
    const float* psz = ps + ((long)z * 32) * 2048 + q;
    float mx = -3.4e38f;
    #pragma unroll
    for (int j = 0; j < 32; ++j) mx = fmaxf(mx, pmz[j * 2048]);
    float s = 0.f;
    #pragma unroll
    for (int j = 0; j < 32; ++j)
        s += psz[j * 2048] * exp2f(pmz[j * 2048] - mx);
    const float L = mx + log2f(s);
    float* sc = scale + ((long)z * 32) * 2048 + q;
    #pragma unroll
    for (int j = 0; j < 32; ++j)
        sc[j * 2048] = exp2f(pmz[j * 2048] - L);
}

// ---------------------------------------------------------------------------
// in-place rescale: e[z][kk][q] *= scale[z][kk>>6][q]
// ---------------------------------------------------------------------------
__global__ __launch_bounds__(256)
void rescale_e(f16* __restrict__ e, const float* __restrict__ scale, long n8)
{
    const long idx = (long)blockIdx.x * 256 + threadIdx.x;
    if (idx >= n8) return;
    const long z = idx >> 19;
    const int within = (int)(idx & ((1 << 19) - 1));
    const int kk = within >> 8;
    const int q8 = (within & 255) * 8;
    const float* sc = scale + ((long)z * 32 + (kk >> 6)) * 2048 + q8;
    const float4 s0 = *(const float4*)sc;
    const float4 s1 = *(const float4*)(sc + 4);
    f16x8 v = *(f16x8*)(e + idx * 8);
    v[0] = (f16)((float)v[0] * s0.x); v[1] = (f16)((float)v[1] * s0.y);
    v[2] = (f16)((float)v[2] * s0.z); v[3] = (f16)((float)v[3] * s0.w);
    v[4] = (f16)((float)v[4] * s1.x); v[5] = (f16)((float)v[5] * s1.y);
    v[6] = (f16)((float)v[6] * s1.z); v[7] = (f16)((float)v[7] * s1.w);
    *(f16x8*)(e + idx * 8) = v;
}

// ---------------------------------------------------------------------------
__global__ __launch_bounds__(256)
void copy_q_kernel(const float* __restrict__ q, float* __restrict__ out, long n4)
{
    const long idx = (long)blockIdx.x * 256 + threadIdx.x;
    if (idx >= n4) return;
    const long row = idx >> 8;
    const long c4 = idx & 255;
    *(float4*)(&out[row * 2048 + c4 * 4]) =
        *(const float4*)(&q[row * 1024 + c4 * 4]);
}

// ===========================================================================
// fp32 fallback for small workspaces
// ===========================================================================
#define BM 64
#define BN 64
#define BKF 16
template<int opA, int opB>
__global__ __launch_bounds__(256)
void sgemm(const float* __restrict__ A, const float* __restrict__ B,
           float* __restrict__ C,
           int M, int N, int K, int lda, int ldb, int ldc)
{
    __shared__ float As[BKF][BM];
    __shared__ float Bs[BKF][BN];
    const int tid = threadIdx.x;
    const int tx = tid & 15, ty = tid >> 4;
    const int bm = blockIdx.y * BM, bn = blockIdx.x * BN;
    float acc[4][4] = {};
    for (int k0 = 0; k0 < K; k0 += BKF) {
        if (opA == 0) {
            const int row = tid >> 2, kq = (tid & 3) * 4;
            const float4 v = *(const float4*)(A + (long)(bm + row) * lda + (k0 + kq));
            As[kq + 0][row] = v.x; As[kq + 1][row] = v.y;
            As[kq + 2][row] = v.z; As[kq + 3][row] = v.w;
        } else {
            const int kk = tid >> 4, mq = (tid & 15) * 4;
            *(float4*)(&As[kk][mq]) =
                *(const float4*)(A + (long)(k0 + kk) * lda + (bm + mq));
        }
        if (opB == 0) {
            const int kk = tid >> 4, nq = (tid & 15) * 4;
            *(float4*)(&Bs[kk][nq]) =
                *(const float4*)(B + (long)(k0 + kk) * ldb + (bn + nq));
        } else {
            const int row = tid >> 2, kq = (tid & 3) * 4;
            const float4 v = *(const float4*)(B + (long)(bn + row) * ldb + (k0 + kq));
            Bs[kq + 0][row] = v.x; Bs[kq + 1][row] = v.y;
            Bs[kq + 2][row] = v.z; Bs[kq + 3][row] = v.w;
        }
        __syncthreads();
        #pragma unroll
        for (int kk = 0; kk < BKF; ++kk) {
            const float4 a = *(const float4*)(&As[kk][ty * 4]);
            const float4 b = *(const float4*)(&Bs[kk][tx * 4]);
            const float av[4] = {a.x, a.y, a.z, a.w};
            const float bv[4] = {b.x, b.y, b.z, b.w};
            #pragma unroll
            for (int i = 0; i < 4; ++i)
                #pragma unroll
                for (int j = 0; j < 4; ++j)
                    acc[i][j] += av[i] * bv[j];
        }
        __syncthreads();
    }
    #pragma unroll
    for (int i = 0; i < 4; ++i) {
        const float4 v = make_float4(acc[i][0], acc[i][1], acc[i][2], acc[i][3]);
        *(float4*)(&C[(long)(bm + ty * 4 + i) * ldc + (bn + tx * 4)]) = v;
    }
}

__device__ __forceinline__ float wave_reduce_max(float v) {
    #pragma unroll
    for (int off = 1; off < 64; off <<= 1)
        v = fmaxf(v, __shfl_xor(v, off, 64));
    return v;
}
__device__ __forceinline__ float wave_reduce_sum(float v) {
    #pragma unroll
    for (int off = 1; off < 64; off <<= 1)
        v += __shfl_xor(v, off, 64);
    return v;
}

__global__ __launch_bounds__(256)
void softmax_rows2048(float* __restrict__ X)
{
    float* x = X + (long)blockIdx.x * 2048;
    const int tid = threadIdx.x;
    float4 v0 = *(const float4*)(&x[tid * 4]);
    float4 v1 = *(const float4*)(&x[1024 + tid * 4]);
    float m = fmaxf(fmaxf(fmaxf(v0.x, v0.y), fmaxf(v0.z, v0.w)),
                    fmaxf(fmaxf(v1.x, v1.y), fmaxf(v1.z, v1.w)));
    m = wave_reduce_max(m);
    __shared__ float sm[4];
    __shared__ float ss[4];
    const int wid = tid >> 6;
    if ((tid & 63) == 0) sm[wid] = m;
    __syncthreads();
    m = fmaxf(fmaxf(sm[0], sm[1]), fmaxf(sm[2], sm[3]));
    v0.x = expf(v0.x - m); v0.y = expf(v0.y - m);
    v0.z = expf(v0.z - m); v0.w = expf(v0.w - m);
    v1.x = expf(v1.x - m); v1.y = expf(v1.y - m);
    v1.z = expf(v1.z - m); v1.w = expf(v1.w - m);
    float s = (v0.x + v0.y + v0.z + v0.w) + (v1.x + v1.y + v1.z + v1.w);
    s = wave_reduce_sum(s);
    if ((tid & 63) == 0) ss[wid] = s;
    __syncthreads();
    s = ss[0] + ss[1] + ss[2] + ss[3];
    const float inv = 1.0f / s;
    v0.x *= inv; v0.y *= inv; v0.z *= inv; v0.w *= inv;
    v1.x *= inv; v1.y *= inv; v1.z *= inv; v1.w *= inv;
    *(float4*)(&x[tid * 4]) = v0;
    *(float4*)(&x[1024 + tid * 4]) = v1;
}

static void fallback_fp32(const float* q, const float* k, const float* Wq,
                          const float* Wk, const float* Wv, float* out,
                          void* d_ws, hipStream_t stream)
{
    const int S = 2048, D = 1024, O = 1024, B = 8;
    float* qp = (float*)d_ws;
    float* kp = qp + (size_t)S * O;
    float* vp = kp + (size_t)S * O;
    float* attn = vp + (size_t)S * O;
    const long n4 = (long)B * S * D / 4;
    copy_q_kernel<<<dim3((n4 + 255) / 256), 256, 0, stream>>>(q, out, n4);
    const dim3 blk(256);
    const dim3 gproj(O / BN, S / BM), gattn(S / BN, S / BM), gctx(O / BN, S / BM);
    for (int b = 0; b < B; ++b) {
        const float* qb = q + (size_t)b * S * D;
        const float* kb = k + (size_t)b * S * D;
        float* outc = out + (size_t)b * S * 2048 + D;
        sgemm<0, 0><<<gproj, blk, 0, stream>>>(qb, Wq, qp, S, O, D, D, O, O);
        sgemm<0, 0><<<gproj, blk, 0, stream>>>(kb, Wk, kp, S, O, D, D, O, O);
        sgemm<0, 0><<<gproj, blk, 0, stream>>>(kb, Wv, vp, S, O, D, D, O, O);
        sgemm<0, 1><<<gattn, blk, 0, stream>>>(qp, kp, attn, S, S, O, O, O, S);
        softmax_rows2048<<<dim3(S), blk, 0, stream>>>(attn);
        sgemm<1, 0><<<gctx, blk, 0, stream>>>(attn, vp, outc, S, O, S, S, O, 2048);
    }
}

// ===========================================================================
extern "C" void kernel_launch(void* const* d_in, const int* in_sizes, int n_in,
                              void* d_out, int out_size, void* d_ws, size_t ws_size,
                              hipStream_t stream)
{
    const float* q  = (const float*)d_in[0];
    const float* k  = (const float*)d_in[1];
    const float* Wq = (const float*)d_in[2];
    const float* Wk = (const float*)d_in[3];
    const float* Wv = (const float*)d_in[4];
    float* out = (float*)d_out;

    const int B = 8, S = 2048;

    auto need = [](int g) -> size_t {
        const size_t wpk = 3 * (size_t)1024 * 1024 * 2;
        const size_t pkA = (size_t)g * 2048 * 1024 * 2;   // qpack,kpack,qp,kp
        const size_t vpT = (size_t)1024 * g * 2048 * 2;
        const size_t aw  = (size_t)g * 2048 * 2048 * 2;
        const size_t pp  = 3 * (size_t)g * 32 * 2048 * 4;
        return wpk + 4 * pkA + vpT + aw + pp + 32 * 256;
    };
    int g = 0;
    for (int cand : {8, 4, 2, 1})
        if (need(cand) <= ws_size) { g = cand; break; }
    if (g == 0) { fallback_fp32(q, k, Wq, Wk, Wv, out, d_ws, stream); return; }

    char* p = (char*)d_ws;
    auto carve = [&](size_t bytes) {
        char* r = p;
        p += (bytes + 255) & ~(size_t)255;
        return r;
    };
    // NOTE: Wtq/Wtk/Wtv contiguous (2 MiB each); qpack/kpack contiguous;
    // qp/kp contiguous — CM_PROJ3 relies on this.
    f16* Wtq = (f16*)carve((size_t)1024 * 1024 * 2);
    f16* Wtk = (f16*)carve((size_t)1024 * 1024 * 2);
    f16* Wtv = (f16*)carve((size_t)1024 * 1024 * 2);
    const size_t pkAB = (size_t)g * 2048 * 1024 * 2;
    f16* qpack   = (f16*)carve(pkAB);
    f16* kpack   = (f16*)carve(pkAB);
    f16* qp_pack = (f16*)carve(pkAB);
    f16* kp_pack = (f16*)carve(pkAB);
    f16* vpT     = (f16*)carve((size_t)1024 * g * 2048 * 2);
    f16* attn_w  = (f16*)carve((size_t)g * 2048 * 2048 * 2);
    float* pmb   = (float*)carve((size_t)g * 32 * 2048 * 4);
    float* psb   = (float*)carve((size_t)g * 32 * 2048 * 4);
    float* scb   = (float*)carve((size_t)g * 32 * 2048 * 4);

    pack_W_T<<<dim3(16, 16), 256, 0, stream>>>(Wq, Wtq);
    pack_W_T<<<dim3(16, 16), 256, 0, stream>>>(Wk, Wtk);
    pack_W_T<<<dim3(16, 16), 256, 0, stream>>>(Wv, Wtv);

    const int Mg = g * 2048;
    const dim3 blk(256);
    const long zSS = (long)2048 * 2048;
    const long zSD = (long)2048 * 1024;

    for (int gi = 0; gi < B / g; ++gi) {
        const float* qg = q + (size_t)gi * Mg * 1024;
        const float* kg = k + (size_t)gi * Mg * 1024;
        float* outq = out + (size_t)gi * Mg * 2048;

        const long nquads = (long)Mg * 256;
        pack_cast_q<<<dim3((nquads + 255) / 256), blk, 0, stream>>>(
            qg, qpack, outq, nquads);
        pack_cast_k<<<dim3((nquads + 255) / 256), blk, 0, stream>>>(
            kg, kpack, nquads);

        // fused projections: grid.y=3 -> {qp, kp, vpT}
        const dim3 g1((1024 / 128) * (Mg / 128), 3, 1);
        gemm128<CM_PROJ3><<<g1, blk, 0, stream>>>(
            qpack, Wtq, qp_pack, Mg, 1024, 1024, 1024, 1024, 1024, 0, 0, 0,
            (float*)vpT, nullptr);

        // attnT = kp @ qp^T per z (plain f16, K=1024) -> f16 e + partials
        const dim3 g2((2048 / 128) * (2048 / 128), 1, g);
        gemm128<CM_ATTN><<<g2, blk, 0, stream>>>(
            kp_pack, qp_pack, attn_w, 2048, 2048, 1024, 1024, 1024, 2048,
            zSD, zSD, zSS, pmb, psb);

        // merge partials -> scale table; in-place rescale e -> weights
        const int nq = g * 2048;
        softmax_merge32<<<dim3((nq + 255) / 256), blk, 0, stream>>>(pmb, psb, scb, nq);
        const long n8 = (long)g * 2048 * 256;
        rescale_e<<<dim3((n8 + 255) / 256), blk, 0, stream>>>(attn_w, scb, n8);

        // context = attn_w @ vpT^T -> out cols 1024..2047
        float* outg = out + (size_t)gi * Mg * 2048 + 1024;
        const dim3 g3((1024 / 128) * (2048 / 128), 1, g);
        gemm128<CM_F32><<<g3, blk, 0, stream>>>(
            attn_w, vpT, outg, 2048, 1024, 2048, 2048, Mg, 2048,
            zSS, 2048, zSS, nullptr, nullptr);
    }
}

// Round 13
// 362.144 us; speedup vs baseline: 1.1716x; 1.1716x over previous
//
#include <hip/hip_runtime.h>
#include <hip/hip_bf16.h>

// B=8, S=2048, D=1024, O=1024
// qp=q@Wq, kp=k@Wk, vp=k@Wv ; attn=qp@kp^T (no scale); w=softmax(attn,-1)
// context = attn_w^T @ vp ; out = concat([q, context], -1)  fp32 [B,S,2048]
//
// All GEMMs plain fp16 in / fp32 MFMA accumulate. attnT = kp @ qp^T computed
// transposed; ATTN epilogue writes f16 e=exp(l-M_blk) + per-128-row partials;
// merge -> f16 scale table; PV GEMM multiplies its A-frags by the scales
// in-register (CM_PVS) -- no separate rescale pass.
//
// GEMM (r10 config, best known: 377us): 256x256 tile, BK=64, 8 waves (2Mx4N),
// 32x32x16 f16 MFMA, 2 phases/K-tile, counted vmcnt(4), setprio, XCD swizzle,
// conflict-free swizzled LDS, __launch_bounds__(512,2). r8-r12 lessons:
// barrier count / prefetch depth / sched pins / occupancy are all NOT the
// binder (2-phase structure is stall-bound ~30-35% MfmaUtil, cf m233);
// (512,4) spills the accumulator (r9, 15x); 128^2 2-blocks/CU is worse (r12).

typedef __attribute__((ext_vector_type(4))) float f32x4;
typedef __attribute__((ext_vector_type(16))) float f32x16;
typedef _Float16 f16;
typedef __attribute__((ext_vector_type(8))) _Float16 f16x8;
typedef __attribute__((ext_vector_type(4))) _Float16 f16x4;

#define LOG2E 1.4426950408889634f

#define CM_F32     0
#define CM_F16     1
#define CM_F16T    3
#define CM_ATTN    4
#define CM_PROJ3   5
#define CM_PVS     6   // PV with in-register softmax-scale on A-frags

// Stage one 16 KiB unit (WHICH: 0=A,1=B; KS: k-half) of K-tile KT into buffer
// at byte offset BO. LDS dst linear in tid; XOR swizzle applied by
// pre-swizzling the GLOBAL source k-chunk (both-sides-or-neither).
#define STAGE(WHICH, KS, KT, BO) do { \
    const char* _gb = (WHICH) ? Bb : Ab; \
    const int _ld = (WHICH) ? ldb : lda; \
    const long _r = (WHICH) ? (long)(bn + srow0) : (long)(bm + srow0); \
    const int _k0 = (KT) * 64 + (KS) * 32 + sh8; \
    char* _dst = (char*)smem + (BO) + (WHICH) * 32768 + (KS) * 16384 + wave * 1024; \
    const char* _g0 = _gb + ((_r * _ld + _k0) << 1); \
    const char* _g1 = _gb + (((_r + 128) * _ld + _k0) << 1); \
    __builtin_amdgcn_global_load_lds((const __attribute__((address_space(1))) void*)_g0, \
        (__attribute__((address_space(3))) void*)_dst, 16, 0, 0); \
    __builtin_amdgcn_global_load_lds((const __attribute__((address_space(1))) void*)_g1, \
        (__attribute__((address_space(3))) void*)(_dst + 8192), 16, 0, 0); \
} while (0)

// One phase: K-half KS, BOTH k-steps. 12 ds_read_b128 (+2 scale b128 if PVS)
// -> stage issue -> barrier -> [PVS: scale-mul A-frags] -> 16 MFMA -> VM ->
// barrier. Scale element mapping: af[s][mt][j] multiplies sc[q] with
// q = t*64 + KS*32 + s*16 + h5*8 + j (f3-swizzle cancels staging-side).
#define GPHASE2(KS, STAGE_CODE, VM) do { \
    f16x8 af[2][4], bb[2][2], sv[2]; \
    _Pragma("unroll") \
    for (int s = 0; s < 2; ++s) { \
        _Pragma("unroll") \
        for (int mt = 0; mt < 4; ++mt) \
            af[s][mt] = *(const f16x8*)(smem + \
                ((bufo + (KS) * 16384 + abase[mt]) ^ (s << 5))); \
        _Pragma("unroll") \
        for (int nt = 0; nt < 2; ++nt) \
            bb[s][nt] = *(const f16x8*)(smem + \
                ((bufo + (KS) * 16384 + bbase[nt]) ^ (s << 5))); \
        if (CMODE == CM_PVS) \
            sv[s] = *(const f16x8*)(smem + 131072 + wm * 4096 + \
                t * 128 + (KS) * 64 + s * 32 + (h5 << 4)); \
    } \
    STAGE_CODE; \
    __builtin_amdgcn_s_barrier(); \
    if (CMODE == CM_PVS) { \
        _Pragma("unroll") \
        for (int s = 0; s < 2; ++s) \
            _Pragma("unroll") \
            for (int mt = 0; mt < 4; ++mt) \
                af[s][mt] *= sv[s]; \
    } \
    __builtin_amdgcn_s_setprio(1); \
    _Pragma("unroll") \
    for (int s = 0; s < 2; ++s) \
        _Pragma("unroll") \
        for (int mt = 0; mt < 4; ++mt) \
            _Pragma("unroll") \
            for (int nt = 0; nt < 2; ++nt) \
                acc[mt][nt] = __builtin_amdgcn_mfma_f32_32x32x16_f16( \
                    af[s][mt], bb[s][nt], acc[mt][nt], 0, 0, 0); \
    __builtin_amdgcn_s_setprio(0); \
    VM; \
    __builtin_amdgcn_s_barrier(); \
} while (0)

// CM_PROJ3: blockIdx.y selects {q@Wq->qp(F16), k@Wk->kp(F16),
// k@Wv->vpT(F16T via pm, stride M)}. CM_PVS: ps = f16 scale table base
// [z][16][2048].
template<int CMODE>
__global__ __launch_bounds__(512, 2)
void gemm256(const f16* __restrict__ A, const f16* __restrict__ B,
             void* __restrict__ Cv,
             int M, int N, int K, int lda, int ldb, int ldc,
             long az, long bz, long cz,
             float* __restrict__ pm, float* __restrict__ ps)
{
    __shared__ __align__(16) char smem[139264];   // 128K buffers + 8K scales

    const int z = blockIdx.z;
    const char* Ab;
    const char* Bb;
    if (CMODE == CM_PROJ3) {
        const int y = blockIdx.y;
        Ab = (const char*)(A + (y ? (long)M * 1024 : 0));
        Bb = (const char*)(B + (long)y * 1024 * 1024);
    } else {
        Ab = (const char*)(A + z * az);
        Bb = (const char*)(B + z * bz);
    }

    // XCD-aware swizzle (all launches have nwg % 8 == 0)
    const int nbx = N >> 8;
    int wg = blockIdx.x;
    const int nwg = gridDim.x;
    if ((nwg & 7) == 0) wg = (wg & 7) * (nwg >> 3) + (wg >> 3);
    const int bm = (wg / nbx) << 8;
    const int bn = (wg % nbx) << 8;

    const int tid = threadIdx.x;
    const int wave = tid >> 6;
    const int lane = tid & 63;
    const int l31 = lane & 31;
    const int h5 = lane >> 5;
    const int wm = wave >> 2;      // 0..1 -> rows wm*128..+128
    const int wn = wave & 3;       // 0..3 -> cols wn*64..+64

    // swizzled slot: slot = (2*s ^ h5 ^ f) with f = (row ^ row>>2)&3
    const int f3 = (l31 ^ (l31 >> 2)) & 3;
    const int sl = ((h5 ^ f3) << 4);
    int abase[4], bbase[2];
    #pragma unroll
    for (int mt = 0; mt < 4; ++mt)
        abase[mt] = (wm * 128 + mt * 32 + l31) * 64 + sl;
    #pragma unroll
    for (int nt = 0; nt < 2; ++nt)
        bbase[nt] = 32768 + (wn * 64 + nt * 32 + l31) * 64 + sl;

    // staging per-thread constants
    const int srow0 = tid >> 2;
    const int sh8 = ((tid ^ (tid >> 2) ^ (tid >> 4)) & 3) * 8;

    f32x16 acc[4][2];
    #pragma unroll
    for (int mt = 0; mt < 4; ++mt)
        #pragma unroll
        for (int nt = 0; nt < 2; ++nt)
            acc[mt][nt] = (f32x16)(0.f);

    const int nt_k = K >> 6;

    {
        if (CMODE == CM_PVS) {
            // stage this block's 2 scale rows (8 KB contiguous) into LDS
            const char* gsc = (const char*)ps +
                (((long)z * 16 + (bm >> 7)) * 2048) * 2 + tid * 16;
            __builtin_amdgcn_global_load_lds(
                (const __attribute__((address_space(1))) void*)gsc,
                (__attribute__((address_space(3))) void*)
                    ((char*)smem + 131072 + wave * 1024), 16, 0, 0);
        }
        const int t1p = (nt_k > 1) ? 1 : 0;
        STAGE(0, 0, 0, 0);
        STAGE(1, 0, 0, 0);
        STAGE(0, 1, 0, 0);
        STAGE(1, 1, 0, 0);
        STAGE(0, 0, t1p, 65536);
        STAGE(1, 0, t1p, 65536);
        asm volatile("s_waitcnt vmcnt(4)" ::: "memory");
        __builtin_amdgcn_s_barrier();
    }

    for (int t = 0; t < nt_k; ++t) {
        const int bufo = (t & 1) << 16;
        const int nbo = bufo ^ 65536;
        const int t1 = (t + 1 < nt_k) ? t + 1 : nt_k - 1;
        const int t2 = (t + 2 < nt_k) ? t + 2 : nt_k - 1;
        // phase 1: compute KS0; stage t1.KS1 into other buffer.
        GPHASE2(0, { STAGE(0, 1, t1, nbo); STAGE(1, 1, t1, nbo); }, );
        // phase 2: compute KS1; stage t2.KS0 into CURRENT buffer (KS0 reads
        // retired at phase-1 barrier); vmcnt(4) leaves t2's 4 loads in
        // flight, guarantees t1 fully landed.
        GPHASE2(1, { STAGE(0, 0, t2, bufo); STAGE(1, 0, t2, bufo); },
                asm volatile("s_waitcnt vmcnt(4)" ::: "memory"));
    }
    // drain pending LDS-DMA before the workgroup can exit
    asm volatile("s_waitcnt vmcnt(0)" ::: "memory");

    // ---- epilogue: 32x32 D mapping col=lane&31, row=(reg&3)+4*(lane>>5)+8*(reg>>2)
    if (CMODE == CM_ATTN) {
        f16* E = (f16*)Cv + z * cz;
        #pragma unroll
        for (int nt = 0; nt < 2; ++nt) {
            float Mx = -3.4e38f;
            #pragma unroll
            for (int mt = 0; mt < 4; ++mt)
                #pragma unroll
                for (int r = 0; r < 16; ++r)
                    Mx = fmaxf(Mx, acc[mt][nt][r]);
            Mx = fmaxf(Mx, __shfl_xor(Mx, 32, 64));
            float Sm = 0.f;
            #pragma unroll
            for (int mt = 0; mt < 4; ++mt)
                #pragma unroll
                for (int r = 0; r < 16; ++r) {
                    const float e = exp2f((acc[mt][nt][r] - Mx) * LOG2E);
                    acc[mt][nt][r] = e;
                    Sm += e;
                }
            Sm += __shfl_xor(Sm, 32, 64);
            const int col = bn + wn * 64 + nt * 32 + l31;
            #pragma unroll
            for (int mt = 0; mt < 4; ++mt) {
                const int row0 = bm + wm * 128 + mt * 32 + h5 * 4;
                #pragma unroll
                for (int rq = 0; rq < 4; ++rq)
                    #pragma unroll
                    for (int rr = 0; rr < 4; ++rr)
                        E[(long)(row0 + rq * 8 + rr) * ldc + col] =
                            (f16)acc[mt][nt][rq * 4 + rr];
            }
            if (lane < 32) {
                const long pidx = ((long)z * 16 + (bm >> 7) + wm) * N + col;
                pm[pidx] = Mx * LOG2E;   // log2 domain
                ps[pidx] = Sm;
            }
        }
        return;
    }

    #pragma unroll
    for (int mt = 0; mt < 4; ++mt) {
        #pragma unroll
        for (int nt = 0; nt < 2; ++nt) {
            const int row0 = bm + wm * 128 + mt * 32 + h5 * 4;
            const int col = bn + wn * 64 + nt * 32 + l31;
            if (CMODE == CM_F32 || CMODE == CM_PVS) {
                float* C = (float*)Cv + z * cz;
                #pragma unroll
                for (int rq = 0; rq < 4; ++rq)
                    #pragma unroll
                    for (int rr = 0; rr < 4; ++rr)
                        C[(long)(row0 + rq * 8 + rr) * ldc + col] =
                            acc[mt][nt][rq * 4 + rr];
            } else if (CMODE == CM_F16) {
                f16* C = (f16*)Cv + z * cz;
                #pragma unroll
                for (int rq = 0; rq < 4; ++rq)
                    #pragma unroll
                    for (int rr = 0; rr < 4; ++rr)
                        C[(long)(row0 + rq * 8 + rr) * ldc + col] =
                            (f16)acc[mt][nt][rq * 4 + rr];
            } else if (CMODE == CM_F16T) { // C^T[col][rows]
                f16* C = (f16*)Cv + z * cz;
                #pragma unroll
                for (int rq = 0; rq < 4; ++rq) {
                    f16x4 v;
                    #pragma unroll
                    for (int rr = 0; rr < 4; ++rr) v[rr] = (f16)acc[mt][nt][rq * 4 + rr];
                    *(f16x4*)(C + (long)col * ldc + row0 + rq * 8) = v;
                }
            } else { // CM_PROJ3
                const int y = blockIdx.y;
                if (y < 2) {
                    f16* C = (f16*)Cv + (long)y * M * 1024;
                    #pragma unroll
                    for (int rq = 0; rq < 4; ++rq)
                        #pragma unroll
                        for (int rr = 0; rr < 4; ++rr)
                            C[(long)(row0 + rq * 8 + rr) * 1024 + col] =
                                (f16)acc[mt][nt][rq * 4 + rr];
                } else {
                    f16* C = (f16*)pm;   // vpT [1024][M]
                    #pragma unroll
                    for (int rq = 0; rq < 4; ++rq) {
                        f16x4 v;
                        #pragma unroll
                        for (int rr = 0; rr < 4; ++rr)
                            v[rr] = (f16)acc[mt][nt][rq * 4 + rr];
                        *(f16x4*)(C + (long)col * M + row0 + rq * 8) = v;
                    }
                }
            }
        }
    }
}

// ---------------------------------------------------------------------------
// fused cast: q rows -> f16 + fp32 copy into out[:,0:1024]; k rows -> f16
// idx < nquads: q part; else k part.
// ---------------------------------------------------------------------------
__global__ __launch_bounds__(256)
void pack_cast_qk(const float* __restrict__ qin, const float* __restrict__ kin,
                  f16* __restrict__ qp, f16* __restrict__ kp,
                  float* __restrict__ oq, long nquads)
{
    const long i = (long)blockIdx.x * 256 + threadIdx.x;
    if (i >= 2 * nquads) return;
    const int isK = (i >= nquads);
    const long j = isK ? i - nquads : i;
    const long row = j >> 8;
    const int c = (int)(j & 255) * 4;
    const float4 v = isK ? *(const float4*)(kin + row * 1024 + c)
                         : *(const float4*)(qin + row * 1024 + c);
    f16x4 h;
    h[0] = (f16)v.x; h[1] = (f16)v.y; h[2] = (f16)v.z; h[3] = (f16)v.w;
    if (isK) {
        *(f16x4*)(kp + row * 1024 + c) = h;
    } else {
        *(float4*)(oq + row * 2048 + c) = v;
        *(f16x4*)(qp + row * 1024 + c) = h;
    }
}

// ---------------------------------------------------------------------------
// W [1024 d][1024 o] fp32 -> Wt [1024 o][1024 d] f16 (transpose + cast)
// ---------------------------------------------------------------------------
__global__ __launch_bounds__(256)
void pack_W_T(const float* __restrict__ W, f16* __restrict__ Wt)
{
    __shared__ float tile[64][65];
    const int d0 = blockIdx.y * 64, o0 = blockIdx.x * 64;
    const int t = threadIdx.x;
    const int rr = t >> 4, c4 = (t & 15) * 4;
    #pragma unroll
    for (int it = 0; it < 4; ++it) {
        const int r = rr + it * 16;
        const float4 v = *(const float4*)(W + (long)(d0 + r) * 1024 + o0 + c4);
        tile[r][c4] = v.x; tile[r][c4 + 1] = v.y;
        tile[r][c4 + 2] = v.z; tile[r][c4 + 3] = v.w;
    }
    __syncthreads();
    #pragma unroll
    for (int it = 0; it < 4; ++it) {
        const int orow = rr + it * 16;
        f16x4 h;
        #pragma unroll
        for (int j = 0; j < 4; ++j) h[j] = (f16)tile[c4 + j][orow];
        *(f16x4*)(Wt + (long)(o0 + orow) * 1024 + d0 + c4) = h;
    }
}

// ---------------------------------------------------------------------------
// merge 16 per-block partials -> f16 scale[z][16][2048] = exp2(pm - L)
// ---------------------------------------------------------------------------
__global__ __launch_bounds__(256)
void softmax_merge16(const float* __restrict__ pm, const float* __restrict__ ps,
                     f16* __restrict__ scale, int nq)
{
    const int idx = blockIdx.x * 256 + threadIdx.x;
    if (idx >= nq) return;
    const int z = idx >> 11, q = idx & 2047;
    const float* pmz = pm + ((long)z * 16) * 2048 + q;
    const float* psz = ps + ((long)z * 16) * 2048 + q;
    float mx = -3.4e38f;
    #pragma unroll
    for (int j = 0; j < 16; ++j) mx = fmaxf(mx, pmz[j * 2048]);
    float s = 0.f;
    #pragma unroll
    for (int j = 0; j < 16; ++j)
        s += psz[j * 2048] * exp2f(pmz[j * 2048] - mx);
    const float L = mx + log2f(s);
    f16* sc = scale + ((long)z * 16) * 2048 + q;
    #pragma unroll
    for (int j = 0; j < 16; ++j)
        sc[j * 2048] = (f16)exp2f(pmz[j * 2048] - L);
}

// ---------------------------------------------------------------------------
__global__ __launch_bounds__(256)
void copy_q_kernel(const float* __restrict__ q, float* __restrict__ out, long n4)
{
    const long idx = (long)blockIdx.x * 256 + threadIdx.x;
    if (idx >= n4) return;
    const long row = idx >> 8;
    const long c4 = idx & 255;
    *(float4*)(&out[row * 2048 + c4 * 4]) =
        *(const float4*)(&q[row * 1024 + c4 * 4]);
}

// ===========================================================================
// fp32 fallback for small workspaces
// ===========================================================================
#define BM 64
#define BN 64
#define BKF 16
template<int opA, int opB>
__global__ __launch_bounds__(256)
void sgemm(const float* __restrict__ A, const float* __restrict__ B,
           float* __restrict__ C,
           int M, int N, int K, int lda, int ldb, int ldc)
{
    __shared__ float As[BKF][BM];
    __shared__ float Bs[BKF][BN];
    const int tid = threadIdx.x;
    const int tx = tid & 15, ty = tid >> 4;
    const int bm = blockIdx.y * BM, bn = blockIdx.x * BN;
    float acc[4][4] = {};
    for (int k0 = 0; k0 < K; k0 += BKF) {
        if (opA == 0) {
            const int row = tid >> 2, kq = (tid & 3) * 4;
            const float4 v = *(const float4*)(A + (long)(bm + row) * lda + (k0 + kq));
            As[kq + 0][row] = v.x; As[kq + 1][row] = v.y;
            As[kq + 2][row] = v.z; As[kq + 3][row] = v.w;
        } else {
            const int kk = tid >> 4, mq = (tid & 15) * 4;
            *(float4*)(&As[kk][mq]) =
                *(const float4*)(A + (long)(k0 + kk) * lda + (bm + mq));
        }
        if (opB == 0) {
            const int kk = tid >> 4, nq = (tid & 15) * 4;
            *(float4*)(&Bs[kk][nq]) =
                *(const float4*)(B + (long)(k0 + kk) * ldb + (bn + nq));
        } else {
            const int row = tid >> 2, kq = (tid & 3) * 4;
            const float4 v = *(const float4*)(B + (long)(bn + row) * ldb + (k0 + kq));
            Bs[kq + 0][row] = v.x; Bs[kq + 1][row] = v.y;
            Bs[kq + 2][row] = v.z; Bs[kq + 3][row] = v.w;
        }
        __syncthreads();
        #pragma unroll
        for (int kk = 0; kk < BKF; ++kk) {
            const float4 a = *(const float4*)(&As[kk][ty * 4]);
            const float4 b = *(const float4*)(&Bs[kk][tx * 4]);
            const float av[4] = {a.x, a.y, a.z, a.w};
            const float bv[4] = {b.x, b.y, b.z, b.w};
            #pragma unroll
            for (int i = 0; i < 4; ++i)
                #pragma unroll
                for (int j = 0; j < 4; ++j)
                    acc[i][j] += av[i] * bv[j];
        }
        __syncthreads();
    }
    #pragma unroll
    for (int i = 0; i < 4; ++i) {
        const float4 v = make_float4(acc[i][0], acc[i][1], acc[i][2], acc[i][3]);
        *(float4*)(&C[(long)(bm + ty * 4 + i) * ldc + (bn + tx * 4)]) = v;
    }
}

__device__ __forceinline__ float wave_reduce_max(float v) {
    #pragma unroll
    for (int off = 1; off < 64; off <<= 1)
        v = fmaxf(v, __shfl_xor(v, off, 64));
    return v;
}
__device__ __forceinline__ float wave_reduce_sum(float v) {
    #pragma unroll
    for (int off = 1; off < 64; off <<= 1)
        v += __shfl_xor(v, off, 64);
    return v;
}

__global__ __launch_bounds__(256)
void softmax_rows2048(float* __restrict__ X)
{
    float* x = X + (long)blockIdx.x * 2048;
    const int tid = threadIdx.x;
    float4 v0 = *(const float4*)(&x[tid * 4]);
    float4 v1 = *(const float4*)(&x[1024 + tid * 4]);
    float m = fmaxf(fmaxf(fmaxf(v0.x, v0.y), fmaxf(v0.z, v0.w)),
                    fmaxf(fmaxf(v1.x, v1.y), fmaxf(v1.z, v1.w)));
    m = wave_reduce_max(m);
    __shared__ float sm[4];
    __shared__ float ss[4];
    const int wid = tid >> 6;
    if ((tid & 63) == 0) sm[wid] = m;
    __syncthreads();
    m = fmaxf(fmaxf(sm[0], sm[1]), fmaxf(sm[2], sm[3]));
    v0.x = expf(v0.x - m); v0.y = expf(v0.y - m);
    v0.z = expf(v0.z - m); v0.w = expf(v0.w - m);
    v1.x = expf(v1.x - m); v1.y = expf(v1.y - m);
    v1.z = expf(v1.z - m); v1.w = expf(v1.w - m);
    float s = (v0.x + v0.y + v0.z + v0.w) + (v1.x + v1.y + v1.z + v1.w);
    s = wave_reduce_sum(s);
    if ((tid & 63) == 0) ss[wid] = s;
    __syncthreads();
    s = ss[0] + ss[1] + ss[2] + ss[3];
    const float inv = 1.0f / s;
    v0.x *= inv; v0.y *= inv; v0.z *= inv; v0.w *= inv;
    v1.x *= inv; v1.y *= inv; v1.z *= inv; v1.w *= inv;
    *(float4*)(&x[tid * 4]) = v0;
    *(float4*)(&x[1024 + tid * 4]) = v1;
}

static void fallback_fp32(const float* q, const float* k, const float* Wq,
                          const float* Wk, const float* Wv, float* out,
                          void* d_ws, hipStream_t stream)
{
    const int S = 2048, D = 1024, O = 1024, B = 8;
    float* qp = (float*)d_ws;
    float* kp = qp + (size_t)S * O;
    float* vp = kp + (size_t)S * O;
    float* attn = vp + (size_t)S * O;
    const long n4 = (long)B * S * D / 4;
    copy_q_kernel<<<dim3((n4 + 255) / 256), 256, 0, stream>>>(q, out, n4);
    const dim3 blk(256);
    const dim3 gproj(O / BN, S / BM), gattn(S / BN, S / BM), gctx(O / BN, S / BM);
    for (int b = 0; b < B; ++b) {
        const float* qb = q + (size_t)b * S * D;
        const float* kb = k + (size_t)b * S * D;
        float* outc = out + (size_t)b * S * 2048 + D;
        sgemm<0, 0><<<gproj, blk, 0, stream>>>(qb, Wq, qp, S, O, D, D, O, O);
        sgemm<0, 0><<<gproj, blk, 0, stream>>>(kb, Wk, kp, S, O, D, D, O, O);
        sgemm<0, 0><<<gproj, blk, 0, stream>>>(kb, Wv, vp, S, O, D, D, O, O);
        sgemm<0, 1><<<gattn, blk, 0, stream>>>(qp, kp, attn, S, S, O, O, O, S);
        softmax_rows2048<<<dim3(S), blk, 0, stream>>>(attn);
        sgemm<1, 0><<<gctx, blk, 0, stream>>>(attn, vp, outc, S, O, S, S, O, 2048);
    }
}

// ===========================================================================
extern "C" void kernel_launch(void* const* d_in, const int* in_sizes, int n_in,
                              void* d_out, int out_size, void* d_ws, size_t ws_size,
                              hipStream_t stream)
{
    const float* q  = (const float*)d_in[0];
    const float* k  = (const float*)d_in[1];
    const float* Wq = (const float*)d_in[2];
    const float* Wk = (const float*)d_in[3];
    const float* Wv = (const float*)d_in[4];
    float* out = (float*)d_out;

    const int B = 8, S = 2048;

    auto need = [](int g) -> size_t {
        const size_t wpk = 3 * (size_t)1024 * 1024 * 2;
        const size_t pkA = (size_t)g * 2048 * 1024 * 2;   // qpack,kpack,qp,kp
        const size_t vpT = (size_t)1024 * g * 2048 * 2;
        const size_t aw  = (size_t)g * 2048 * 2048 * 2;
        const size_t pp  = 2 * (size_t)g * 16 * 2048 * 4 + (size_t)g * 16 * 2048 * 2;
        return wpk + 4 * pkA + vpT + aw + pp + 32 * 256;
    };
    int g = 0;
    for (int cand : {8, 4, 2, 1})
        if (need(cand) <= ws_size) { g = cand; break; }
    if (g == 0) { fallback_fp32(q, k, Wq, Wk, Wv, out, d_ws, stream); return; }

    char* p = (char*)d_ws;
    auto carve = [&](size_t bytes) {
        char* r = p;
        p += (bytes + 255) & ~(size_t)255;
        return r;
    };
    // NOTE: Wtq/Wtk/Wtv contiguous (2 MiB each); qpack/kpack contiguous;
    // qp/kp contiguous — CM_PROJ3 relies on this.
    f16* Wtq = (f16*)carve((size_t)1024 * 1024 * 2);
    f16* Wtk = (f16*)carve((size_t)1024 * 1024 * 2);
    f16* Wtv = (f16*)carve((size_t)1024 * 1024 * 2);
    const size_t pkAB = (size_t)g * 2048 * 1024 * 2;
    f16* qpack   = (f16*)carve(pkAB);
    f16* kpack   = (f16*)carve(pkAB);
    f16* qp_pack = (f16*)carve(pkAB);
    f16* kp_pack = (f16*)carve(pkAB);
    f16* vpT     = (f16*)carve((size_t)1024 * g * 2048 * 2);
    f16* attn_w  = (f16*)carve((size_t)g * 2048 * 2048 * 2);
    float* pmb   = (float*)carve((size_t)g * 16 * 2048 * 4);
    float* psb   = (float*)carve((size_t)g * 16 * 2048 * 4);
    f16* scb     = (f16*)carve((size_t)g * 16 * 2048 * 2);

    pack_W_T<<<dim3(16, 16), 256, 0, stream>>>(Wq, Wtq);
    pack_W_T<<<dim3(16, 16), 256, 0, stream>>>(Wk, Wtk);
    pack_W_T<<<dim3(16, 16), 256, 0, stream>>>(Wv, Wtv);

    const int Mg = g * 2048;
    const dim3 blk(256);
    const dim3 blk512(512);
    const long zSS = (long)2048 * 2048;
    const long zSD = (long)2048 * 1024;

    for (int gi = 0; gi < B / g; ++gi) {
        const float* qg = q + (size_t)gi * Mg * 1024;
        const float* kg = k + (size_t)gi * Mg * 1024;
        float* outq = out + (size_t)gi * Mg * 2048;

        const long nquads = (long)Mg * 256;
        pack_cast_qk<<<dim3((2 * nquads + 255) / 256), blk, 0, stream>>>(
            qg, kg, qpack, kpack, outq, nquads);

        // fused projections: grid.y=3 -> {qp, kp, vpT}
        const dim3 g1((1024 / 256) * (Mg / 256), 3, 1);
        gemm256<CM_PROJ3><<<g1, blk512, 0, stream>>>(
            qpack, Wtq, qp_pack, Mg, 1024, 1024, 1024, 1024, 1024, 0, 0, 0,
            (float*)vpT, nullptr);

        // attnT = kp @ qp^T per z (plain f16, K=1024) -> f16 e + partials
        const dim3 g2((2048 / 256) * (2048 / 256), 1, g);
        gemm256<CM_ATTN><<<g2, blk512, 0, stream>>>(
            kp_pack, qp_pack, attn_w, 2048, 2048, 1024, 1024, 1024, 2048,
            zSD, zSD, zSS, pmb, psb);

        // merge partials -> f16 scale table
        const int nq = g * 2048;
        softmax_merge16<<<dim3((nq + 255) / 256), blk, 0, stream>>>(pmb, psb, scb, nq);

        // context = (e*scale) @ vpT^T -> out cols 1024..2047 (scale in-GEMM)
        float* outg = out + (size_t)gi * Mg * 2048 + 1024;
        const dim3 g3((1024 / 256) * (2048 / 256), 1, g);
        gemm256<CM_PVS><<<g3, blk512, 0, stream>>>(
            attn_w, vpT, outg, 2048, 1024, 2048, 2048, Mg, 2048,
            zSS, 2048, zSS, nullptr, (float*)scb);
    }
}

// Round 14
// 361.196 us; speedup vs baseline: 1.1746x; 1.0026x over previous
//
#include <hip/hip_runtime.h>
#include <hip/hip_bf16.h>

// B=8, S=2048, D=1024, O=1024
// qp=q@Wq, kp=k@Wk, vp=k@Wv ; attn=qp@kp^T (no scale); w=softmax(attn,-1)
// context = attn_w^T @ vp ; out = concat([q, context], -1)  fp32 [B,S,2048]
//
// All GEMMs plain fp16 in / fp32 MFMA accumulate. attnT = kp @ qp^T computed
// transposed; ATTN epilogue writes f16 e=exp(l-M_blk) + per-128-row partials;
// merge -> f16 scale table; PV GEMM multiplies its A-frags by the scales
// in-register (CM_PVS) -- no separate rescale pass.
//
// GEMM: 256x256 tile, BK=64, 8 waves (2Mx4N), 32x32x16 f16 MFMA,
// 2 phases/K-tile, counted vmcnt(4), setprio, XCD swizzle, conflict-free
// swizzled LDS, __launch_bounds__(512,2).
// r14 change (m196 lever): STAGE gload issues moved INSIDE the MFMA cluster
// (after the phase-entry barrier) so the VMEM issues + addr-VALU hide in the
// MFMA pipe's idle issue slots instead of contending with the 12 ds_reads.
// PVS scale-mul moved pre-barrier (overlaps other waves' ds_reads).
// r8-r12 lessons: barrier count / prefetch depth / sched pins / occupancy
// are NOT the binder; (512,4) spills the accumulator (r9, 15x); 128^2
// 2-blocks/CU is worse (r12).

typedef __attribute__((ext_vector_type(4))) float f32x4;
typedef __attribute__((ext_vector_type(16))) float f32x16;
typedef _Float16 f16;
typedef __attribute__((ext_vector_type(8))) _Float16 f16x8;
typedef __attribute__((ext_vector_type(4))) _Float16 f16x4;

#define LOG2E 1.4426950408889634f

#define CM_F32     0
#define CM_F16     1
#define CM_F16T    3
#define CM_ATTN    4
#define CM_PROJ3   5
#define CM_PVS     6   // PV with in-register softmax-scale on A-frags

// Stage one 16 KiB unit (WHICH: 0=A,1=B; KS: k-half) of K-tile KT into buffer
// at byte offset BO. LDS dst linear in tid; XOR swizzle applied by
// pre-swizzling the GLOBAL source k-chunk (both-sides-or-neither).
#define STAGE(WHICH, KS, KT, BO) do { \
    const char* _gb = (WHICH) ? Bb : Ab; \
    const int _ld = (WHICH) ? ldb : lda; \
    const long _r = (WHICH) ? (long)(bn + srow0) : (long)(bm + srow0); \
    const int _k0 = (KT) * 64 + (KS) * 32 + sh8; \
    char* _dst = (char*)smem + (BO) + (WHICH) * 32768 + (KS) * 16384 + wave * 1024; \
    const char* _g0 = _gb + ((_r * _ld + _k0) << 1); \
    const char* _g1 = _gb + (((_r + 128) * _ld + _k0) << 1); \
    __builtin_amdgcn_global_load_lds((const __attribute__((address_space(1))) void*)_g0, \
        (__attribute__((address_space(3))) void*)_dst, 16, 0, 0); \
    __builtin_amdgcn_global_load_lds((const __attribute__((address_space(1))) void*)_g1, \
        (__attribute__((address_space(3))) void*)(_dst + 8192), 16, 0, 0); \
} while (0)

// One phase: K-half KS, BOTH k-steps. 12 ds_read_b128 (+2 scale b128 if PVS)
// -> [PVS: scale-mul pre-barrier] -> barrier -> (compiler lgkmcnt) ->
// {STAGE gloads interleaved with 16 MFMA 32x32x16} -> counted vmcnt ->
// barrier. STAGE-write hazards: phase-2's target (bufo.KS0) was last read by
// phase-1 ds_reads which every wave completed before this phase's entry
// barrier; phase-1's target (nbo.KS1) was last read two phases ago.
#define GPHASE2(KS, STAGE_CODE, VM) do { \
    f16x8 af[2][4], bb[2][2], sv[2]; \
    _Pragma("unroll") \
    for (int s = 0; s < 2; ++s) { \
        _Pragma("unroll") \
        for (int mt = 0; mt < 4; ++mt) \
            af[s][mt] = *(const f16x8*)(smem + \
                ((bufo + (KS) * 16384 + abase[mt]) ^ (s << 5))); \
        _Pragma("unroll") \
        for (int nt = 0; nt < 2; ++nt) \
            bb[s][nt] = *(const f16x8*)(smem + \
                ((bufo + (KS) * 16384 + bbase[nt]) ^ (s << 5))); \
        if (CMODE == CM_PVS) \
            sv[s] = *(const f16x8*)(smem + 131072 + wm * 4096 + \
                t * 128 + (KS) * 64 + s * 32 + (h5 << 4)); \
    } \
    if (CMODE == CM_PVS) { \
        _Pragma("unroll") \
        for (int s = 0; s < 2; ++s) \
            _Pragma("unroll") \
            for (int mt = 0; mt < 4; ++mt) \
                af[s][mt] *= sv[s]; \
    } \
    __builtin_amdgcn_s_barrier(); \
    __builtin_amdgcn_s_setprio(1); \
    STAGE_CODE; \
    _Pragma("unroll") \
    for (int s = 0; s < 2; ++s) \
        _Pragma("unroll") \
        for (int mt = 0; mt < 4; ++mt) \
            _Pragma("unroll") \
            for (int nt = 0; nt < 2; ++nt) \
                acc[mt][nt] = __builtin_amdgcn_mfma_f32_32x32x16_f16( \
                    af[s][mt], bb[s][nt], acc[mt][nt], 0, 0, 0); \
    __builtin_amdgcn_s_setprio(0); \
    VM; \
    __builtin_amdgcn_s_barrier(); \
} while (0)

// CM_PROJ3: blockIdx.y selects {q@Wq->qp(F16), k@Wk->kp(F16),
// k@Wv->vpT(F16T via pm, stride M)}. CM_PVS: ps = f16 scale table base
// [z][16][2048].
template<int CMODE>
__global__ __launch_bounds__(512, 2)
void gemm256(const f16* __restrict__ A, const f16* __restrict__ B,
             void* __restrict__ Cv,
             int M, int N, int K, int lda, int ldb, int ldc,
             long az, long bz, long cz,
             float* __restrict__ pm, float* __restrict__ ps)
{
    __shared__ __align__(16) char smem[139264];   // 128K buffers + 8K scales

    const int z = blockIdx.z;
    const char* Ab;
    const char* Bb;
    if (CMODE == CM_PROJ3) {
        const int y = blockIdx.y;
        Ab = (const char*)(A + (y ? (long)M * 1024 : 0));
        Bb = (const char*)(B + (long)y * 1024 * 1024);
    } else {
        Ab = (const char*)(A + z * az);
        Bb = (const char*)(B + z * bz);
    }

    // XCD-aware swizzle (all launches have nwg % 8 == 0)
    const int nbx = N >> 8;
    int wg = blockIdx.x;
    const int nwg = gridDim.x;
    if ((nwg & 7) == 0) wg = (wg & 7) * (nwg >> 3) + (wg >> 3);
    const int bm = (wg / nbx) << 8;
    const int bn = (wg % nbx) << 8;

    const int tid = threadIdx.x;
    const int wave = tid >> 6;
    const int lane = tid & 63;
    const int l31 = lane & 31;
    const int h5 = lane >> 5;
    const int wm = wave >> 2;      // 0..1 -> rows wm*128..+128
    const int wn = wave & 3;       // 0..3 -> cols wn*64..+64

    // swizzled slot: slot = (2*s ^ h5 ^ f) with f = (row ^ row>>2)&3
    const int f3 = (l31 ^ (l31 >> 2)) & 3;
    const int sl = ((h5 ^ f3) << 4);
    int abase[4], bbase[2];
    #pragma unroll
    for (int mt = 0; mt < 4; ++mt)
        abase[mt] = (wm * 128 + mt * 32 + l31) * 64 + sl;
    #pragma unroll
    for (int nt = 0; nt < 2; ++nt)
        bbase[nt] = 32768 + (wn * 64 + nt * 32 + l31) * 64 + sl;

    // staging per-thread constants
    const int srow0 = tid >> 2;
    const int sh8 = ((tid ^ (tid >> 2) ^ (tid >> 4)) & 3) * 8;

    f32x16 acc[4][2];
    #pragma unroll
    for (int mt = 0; mt < 4; ++mt)
        #pragma unroll
        for (int nt = 0; nt < 2; ++nt)
            acc[mt][nt] = (f32x16)(0.f);

    const int nt_k = K >> 6;

    {
        if (CMODE == CM_PVS) {
            // stage this block's 2 scale rows (8 KB contiguous) into LDS
            const char* gsc = (const char*)ps +
                (((long)z * 16 + (bm >> 7)) * 2048) * 2 + tid * 16;
            __builtin_amdgcn_global_load_lds(
                (const __attribute__((address_space(1))) void*)gsc,
                (__attribute__((address_space(3))) void*)
                    ((char*)smem + 131072 + wave * 1024), 16, 0, 0);
        }
        const int t1p = (nt_k > 1) ? 1 : 0;
        STAGE(0, 0, 0, 0);
        STAGE(1, 0, 0, 0);
        STAGE(0, 1, 0, 0);
        STAGE(1, 1, 0, 0);
        STAGE(0, 0, t1p, 65536);
        STAGE(1, 0, t1p, 65536);
        asm volatile("s_waitcnt vmcnt(4)" ::: "memory");
        __builtin_amdgcn_s_barrier();
    }

    for (int t = 0; t < nt_k; ++t) {
        const int bufo = (t & 1) << 16;
        const int nbo = bufo ^ 65536;
        const int t1 = (t + 1 < nt_k) ? t + 1 : nt_k - 1;
        const int t2 = (t + 2 < nt_k) ? t + 2 : nt_k - 1;
        // phase 1: compute KS0; stage t1.KS1 into other buffer.
        GPHASE2(0, { STAGE(0, 1, t1, nbo); STAGE(1, 1, t1, nbo); }, );
        // phase 2: compute KS1; stage t2.KS0 into CURRENT buffer (KS0 reads
        // retired before this phase's entry barrier); vmcnt(4) leaves t2's 4
        // loads in flight, guarantees t1 fully landed.
        GPHASE2(1, { STAGE(0, 0, t2, bufo); STAGE(1, 0, t2, bufo); },
                asm volatile("s_waitcnt vmcnt(4)" ::: "memory"));
    }
    // drain pending LDS-DMA before the workgroup can exit
    asm volatile("s_waitcnt vmcnt(0)" ::: "memory");

    // ---- epilogue: 32x32 D mapping col=lane&31, row=(reg&3)+4*(lane>>5)+8*(reg>>2)
    if (CMODE == CM_ATTN) {
        f16* E = (f16*)Cv + z * cz;
        #pragma unroll
        for (int nt = 0; nt < 2; ++nt) {
            float Mx = -3.4e38f;
            #pragma unroll
            for (int mt = 0; mt < 4; ++mt)
                #pragma unroll
                for (int r = 0; r < 16; ++r)
                    Mx = fmaxf(Mx, acc[mt][nt][r]);
            Mx = fmaxf(Mx, __shfl_xor(Mx, 32, 64));
            float Sm = 0.f;
            #pragma unroll
            for (int mt = 0; mt < 4; ++mt)
                #pragma unroll
                for (int r = 0; r < 16; ++r) {
                    const float e = exp2f((acc[mt][nt][r] - Mx) * LOG2E);
                    acc[mt][nt][r] = e;
                    Sm += e;
                }
            Sm += __shfl_xor(Sm, 32, 64);
            const int col = bn + wn * 64 + nt * 32 + l31;
            #pragma unroll
            for (int mt = 0; mt < 4; ++mt) {
                const int row0 = bm + wm * 128 + mt * 32 + h5 * 4;
                #pragma unroll
                for (int rq = 0; rq < 4; ++rq)
                    #pragma unroll
                    for (int rr = 0; rr < 4; ++rr)
                        E[(long)(row0 + rq * 8 + rr) * ldc + col] =
                            (f16)acc[mt][nt][rq * 4 + rr];
            }
            if (lane < 32) {
                const long pidx = ((long)z * 16 + (bm >> 7) + wm) * N + col;
                pm[pidx] = Mx * LOG2E;   // log2 domain
                ps[pidx] = Sm;
            }
        }
        return;
    }

    #pragma unroll
    for (int mt = 0; mt < 4; ++mt) {
        #pragma unroll
        for (int nt = 0; nt < 2; ++nt) {
            const int row0 = bm + wm * 128 + mt * 32 + h5 * 4;
            const int col = bn + wn * 64 + nt * 32 + l31;
            if (CMODE == CM_F32 || CMODE == CM_PVS) {
                float* C = (float*)Cv + z * cz;
                #pragma unroll
                for (int rq = 0; rq < 4; ++rq)
                    #pragma unroll
                    for (int rr = 0; rr < 4; ++rr)
                        C[(long)(row0 + rq * 8 + rr) * ldc + col] =
                            acc[mt][nt][rq * 4 + rr];
            } else if (CMODE == CM_F16) {
                f16* C = (f16*)Cv + z * cz;
                #pragma unroll
                for (int rq = 0; rq < 4; ++rq)
                    #pragma unroll
                    for (int rr = 0; rr < 4; ++rr)
                        C[(long)(row0 + rq * 8 + rr) * ldc + col] =
                            (f16)acc[mt][nt][rq * 4 + rr];
            } else if (CMODE == CM_F16T) { // C^T[col][rows]
                f16* C = (f16*)Cv + z * cz;
                #pragma unroll
                for (int rq = 0; rq < 4; ++rq) {
                    f16x4 v;
                    #pragma unroll
                    for (int rr = 0; rr < 4; ++rr) v[rr] = (f16)acc[mt][nt][rq * 4 + rr];
                    *(f16x4*)(C + (long)col * ldc + row0 + rq * 8) = v;
                }
            } else { // CM_PROJ3
                const int y = blockIdx.y;
                if (y < 2) {
                    f16* C = (f16*)Cv + (long)y * M * 1024;
                    #pragma unroll
                    for (int rq = 0; rq < 4; ++rq)
                        #pragma unroll
                        for (int rr = 0; rr < 4; ++rr)
                            C[(long)(row0 + rq * 8 + rr) * 1024 + col] =
                                (f16)acc[mt][nt][rq * 4 + rr];
                } else {
                    f16* C = (f16*)pm;   // vpT [1024][M]
                    #pragma unroll
                    for (int rq = 0; rq < 4; ++rq) {
                        f16x4 v;
                        #pragma unroll
                        for (int rr = 0; rr < 4; ++rr)
                            v[rr] = (f16)acc[mt][nt][rq * 4 + rr];
                        *(f16x4*)(C + (long)col * M + row0 + rq * 8) = v;
                    }
                }
            }
        }
    }
}

// ---------------------------------------------------------------------------
// fused cast: q rows -> f16 + fp32 copy into out[:,0:1024]; k rows -> f16
// ---------------------------------------------------------------------------
__global__ __launch_bounds__(256)
void pack_cast_qk(const float* __restrict__ qin, const float* __restrict__ kin,
                  f16* __restrict__ qp, f16* __restrict__ kp,
                  float* __restrict__ oq, long nquads)
{
    const long i = (long)blockIdx.x * 256 + threadIdx.x;
    if (i >= 2 * nquads) return;
    const int isK = (i >= nquads);
    const long j = isK ? i - nquads : i;
    const long row = j >> 8;
    const int c = (int)(j & 255) * 4;
    const float4 v = isK ? *(const float4*)(kin + row * 1024 + c)
                         : *(const float4*)(qin + row * 1024 + c);
    f16x4 h;
    h[0] = (f16)v.x; h[1] = (f16)v.y; h[2] = (f16)v.z; h[3] = (f16)v.w;
    if (isK) {
        *(f16x4*)(kp + row * 1024 + c) = h;
    } else {
        *(float4*)(oq + row * 2048 + c) = v;
        *(f16x4*)(qp + row * 1024 + c) = h;
    }
}

// ---------------------------------------------------------------------------
// W trio [1024 d][1024 o] fp32 -> Wt [1024 o][1024 d] f16 (transpose+cast),
// one launch, grid.z selects which W (Wt trio contiguous, 1 MiB elems apart).
// ---------------------------------------------------------------------------
__global__ __launch_bounds__(256)
void pack_W_T3(const float* __restrict__ W0, const float* __restrict__ W1,
               const float* __restrict__ W2, f16* __restrict__ Wt)
{
    __shared__ float tile[64][65];
    const float* W = (blockIdx.z == 0) ? W0 : (blockIdx.z == 1) ? W1 : W2;
    f16* Wo = Wt + (long)blockIdx.z * 1024 * 1024;
    const int d0 = blockIdx.y * 64, o0 = blockIdx.x * 64;
    const int t = threadIdx.x;
    const int rr = t >> 4, c4 = (t & 15) * 4;
    #pragma unroll
    for (int it = 0; it < 4; ++it) {
        const int r = rr + it * 16;
        const float4 v = *(const float4*)(W + (long)(d0 + r) * 1024 + o0 + c4);
        tile[r][c4] = v.x; tile[r][c4 + 1] = v.y;
        tile[r][c4 + 2] = v.z; tile[r][c4 + 3] = v.w;
    }
    __syncthreads();
    #pragma unroll
    for (int it = 0; it < 4; ++it) {
        const int orow = rr + it * 16;
        f16x4 h;
        #pragma unroll
        for (int j = 0; j < 4; ++j) h[j] = (f16)tile[c4 + j][orow];
        *(f16x4*)(Wo + (long)(o0 + orow) * 1024 + d0 + c4) = h;
    }
}

// ---------------------------------------------------------------------------
// merge 16 per-block partials -> f16 scale[z][16][2048] = exp2(pm - L)
// ---------------------------------------------------------------------------
__global__ __launch_bounds__(256)
void softmax_merge16(const float* __restrict__ pm, const float* __restrict__ ps,
                     f16* __restrict__ scale, int nq)
{
    const int idx = blockIdx.x * 256 + threadIdx.x;
    if (idx >= nq) return;
    const int z = idx >> 11, q = idx & 2047;
    const float* pmz = pm + ((long)z * 16) * 2048 + q;
    const float* psz = ps + ((long)z * 16) * 2048 + q;
    float mx = -3.4e38f;
    #pragma unroll
    for (int j = 0; j < 16; ++j) mx = fmaxf(mx, pmz[j * 2048]);
    float s = 0.f;
    #pragma unroll
    for (int j = 0; j < 16; ++j)
        s += psz[j * 2048] * exp2f(pmz[j * 2048] - mx);
    const float L = mx + log2f(s);
    f16* sc = scale + ((long)z * 16) * 2048 + q;
    #pragma unroll
    for (int j = 0; j < 16; ++j)
        sc[j * 2048] = (f16)exp2f(pmz[j * 2048] - L);
}

// ---------------------------------------------------------------------------
__global__ __launch_bounds__(256)
void copy_q_kernel(const float* __restrict__ q, float* __restrict__ out, long n4)
{
    const long idx = (long)blockIdx.x * 256 + threadIdx.x;
    if (idx >= n4) return;
    const long row = idx >> 8;
    const long c4 = idx & 255;
    *(float4*)(&out[row * 2048 + c4 * 4]) =
        *(const float4*)(&q[row * 1024 + c4 * 4]);
}

// ===========================================================================
// fp32 fallback for small workspaces
// ===========================================================================
#define BM 64
#define BN 64
#define BKF 16
template<int opA, int opB>
__global__ __launch_bounds__(256)
void sgemm(const float* __restrict__ A, const float* __restrict__ B,
           float* __restrict__ C,
           int M, int N, int K, int lda, int ldb, int ldc)
{
    __shared__ float As[BKF][BM];
    __shared__ float Bs[BKF][BN];
    const int tid = threadIdx.x;
    const int tx = tid & 15, ty = tid >> 4;
    const int bm = blockIdx.y * BM, bn = blockIdx.x * BN;
    float acc[4][4] = {};
    for (int k0 = 0; k0 < K; k0 += BKF) {
        if (opA == 0) {
            const int row = tid >> 2, kq = (tid & 3) * 4;
            const float4 v = *(const float4*)(A + (long)(bm + row) * lda + (k0 + kq));
            As[kq + 0][row] = v.x; As[kq + 1][row] = v.y;
            As[kq + 2][row] = v.z; As[kq + 3][row] = v.w;
        } else {
            const int kk = tid >> 4, mq = (tid & 15) * 4;
            *(float4*)(&As[kk][mq]) =
                *(const float4*)(A + (long)(k0 + kk) * lda + (bm + mq));
        }
        if (opB == 0) {
            const int kk = tid >> 4, nq = (tid & 15) * 4;
            *(float4*)(&Bs[kk][nq]) =
                *(const float4*)(B + (long)(k0 + kk) * ldb + (bn + nq));
        } else {
            const int row = tid >> 2, kq = (tid & 3) * 4;
            const float4 v = *(const float4*)(B + (long)(bn + row) * ldb + (k0 + kq));
            Bs[kq + 0][row] = v.x; Bs[kq + 1][row] = v.y;
            Bs[kq + 2][row] = v.z; Bs[kq + 3][row] = v.w;
        }
        __syncthreads();
        #pragma unroll
        for (int kk = 0; kk < BKF; ++kk) {
            const float4 a = *(const float4*)(&As[kk][ty * 4]);
            const float4 b = *(const float4*)(&Bs[kk][tx * 4]);
            const float av[4] = {a.x, a.y, a.z, a.w};
            const float bv[4] = {b.x, b.y, b.z, b.w};
            #pragma unroll
            for (int i = 0; i < 4; ++i)
                #pragma unroll
                for (int j = 0; j < 4; ++j)
                    acc[i][j] += av[i] * bv[j];
        }
        __syncthreads();
    }
    #pragma unroll
    for (int i = 0; i < 4; ++i) {
        const float4 v = make_float4(acc[i][0], acc[i][1], acc[i][2], acc[i][3]);
        *(float4*)(&C[(long)(bm + ty * 4 + i) * ldc + (bn + tx * 4)]) = v;
    }
}

__device__ __forceinline__ float wave_reduce_max(float v) {
    #pragma unroll
    for (int off = 1; off < 64; off <<= 1)
        v = fmaxf(v, __shfl_xor(v, off, 64));
    return v;
}
__device__ __forceinline__ float wave_reduce_sum(float v) {
    #pragma unroll
    for (int off = 1; off < 64; off <<= 1)
        v += __shfl_xor(v, off, 64);
    return v;
}

__global__ __launch_bounds__(256)
void softmax_rows2048(float* __restrict__ X)
{
    float* x = X + (long)blockIdx.x * 2048;
    const int tid = threadIdx.x;
    float4 v0 = *(const float4*)(&x[tid * 4]);
    float4 v1 = *(const float4*)(&x[1024 + tid * 4]);
    float m = fmaxf(fmaxf(fmaxf(v0.x, v0.y), fmaxf(v0.z, v0.w)),
                    fmaxf(fmaxf(v1.x, v1.y), fmaxf(v1.z, v1.w)));
    m = wave_reduce_max(m);
    __shared__ float sm[4];
    __shared__ float ss[4];
    const int wid = tid >> 6;
    if ((tid & 63) == 0) sm[wid] = m;
    __syncthreads();
    m = fmaxf(fmaxf(sm[0], sm[1]), fmaxf(sm[2], sm[3]));
    v0.x = expf(v0.x - m); v0.y = expf(v0.y - m);
    v0.z = expf(v0.z - m); v0.w = expf(v0.w - m);
    v1.x = expf(v1.x - m); v1.y = expf(v1.y - m);
    v1.z = expf(v1.z - m); v1.w = expf(v1.w - m);
    float s = (v0.x + v0.y + v0.z + v0.w) + (v1.x + v1.y + v1.z + v1.w);
    s = wave_reduce_sum(s);
    if ((tid & 63) == 0) ss[wid] = s;
    __syncthreads();
    s = ss[0] + ss[1] + ss[2] + ss[3];
    const float inv = 1.0f / s;
    v0.x *= inv; v0.y *= inv; v0.z *= inv; v0.w *= inv;
    v1.x *= inv; v1.y *= inv; v1.z *= inv; v1.w *= inv;
    *(float4*)(&x[tid * 4]) = v0;
    *(float4*)(&x[1024 + tid * 4]) = v1;
}

static void fallback_fp32(const float* q, const float* k, const float* Wq,
                          const float* Wk, const float* Wv, float* out,
                          void* d_ws, hipStream_t stream)
{
    const int S = 2048, D = 1024, O = 1024, B = 8;
    float* qp = (float*)d_ws;
    float* kp = qp + (size_t)S * O;
    float* vp = kp + (size_t)S * O;
    float* attn = vp + (size_t)S * O;
    const long n4 = (long)B * S * D / 4;
    copy_q_kernel<<<dim3((n4 + 255) / 256), 256, 0, stream>>>(q, out, n4);
    const dim3 blk(256);
    const dim3 gproj(O / BN, S / BM), gattn(S / BN, S / BM), gctx(O / BN, S / BM);
    for (int b = 0; b < B; ++b) {
        const float* qb = q + (size_t)b * S * D;
        const float* kb = k + (size_t)b * S * D;
        float* outc = out + (size_t)b * S * 2048 + D;
        sgemm<0, 0><<<gproj, blk, 0, stream>>>(qb, Wq, qp, S, O, D, D, O, O);
        sgemm<0, 0><<<gproj, blk, 0, stream>>>(kb, Wk, kp, S, O, D, D, O, O);
        sgemm<0, 0><<<gproj, blk, 0, stream>>>(kb, Wv, vp, S, O, D, D, O, O);
        sgemm<0, 1><<<gattn, blk, 0, stream>>>(qp, kp, attn, S, S, O, O, O, S);
        softmax_rows2048<<<dim3(S), blk, 0, stream>>>(attn);
        sgemm<1, 0><<<gctx, blk, 0, stream>>>(attn, vp, outc, S, O, S, S, O, 2048);
    }
}

// ===========================================================================
extern "C" void kernel_launch(void* const* d_in, const int* in_sizes, int n_in,
                              void* d_out, int out_size, void* d_ws, size_t ws_size,
                              hipStream_t stream)
{
    const float* q  = (const float*)d_in[0];
    const float* k  = (const float*)d_in[1];
    const float* Wq = (const float*)d_in[2];
    const float* Wk = (const float*)d_in[3];
    const float* Wv = (const float*)d_in[4];
    float* out = (float*)d_out;

    const int B = 8, S = 2048;

    auto need = [](int g) -> size_t {
        const size_t wpk = 3 * (size_t)1024 * 1024 * 2;
        const size_t pkA = (size_t)g * 2048 * 1024 * 2;   // qpack,kpack,qp,kp
        const size_t vpT = (size_t)1024 * g * 2048 * 2;
        const size_t aw  = (size_t)g * 2048 * 2048 * 2;
        const size_t pp  = 2 * (size_t)g * 16 * 2048 * 4 + (size_t)g * 16 * 2048 * 2;
        return wpk + 4 * pkA + vpT + aw + pp + 32 * 256;
    };
    int g = 0;
    for (int cand : {8, 4, 2, 1})
        if (need(cand) <= ws_size) { g = cand; break; }
    if (g == 0) { fallback_fp32(q, k, Wq, Wk, Wv, out, d_ws, stream); return; }

    char* p = (char*)d_ws;
    auto carve = [&](size_t bytes) {
        char* r = p;
        p += (bytes + 255) & ~(size_t)255;
        return r;
    };
    // NOTE: Wtq/Wtk/Wtv contiguous (2 MiB each); qpack/kpack contiguous;
    // qp/kp contiguous — CM_PROJ3 and pack_W_T3 rely on this.
    f16* Wtq = (f16*)carve((size_t)1024 * 1024 * 2);
    f16* Wtk = (f16*)carve((size_t)1024 * 1024 * 2);
    f16* Wtv = (f16*)carve((size_t)1024 * 1024 * 2);
    (void)Wtk; (void)Wtv;
    const size_t pkAB = (size_t)g * 2048 * 1024 * 2;
    f16* qpack   = (f16*)carve(pkAB);
    f16* kpack   = (f16*)carve(pkAB);
    f16* qp_pack = (f16*)carve(pkAB);
    f16* kp_pack = (f16*)carve(pkAB);
    f16* vpT     = (f16*)carve((size_t)1024 * g * 2048 * 2);
    f16* attn_w  = (f16*)carve((size_t)g * 2048 * 2048 * 2);
    float* pmb   = (float*)carve((size_t)g * 16 * 2048 * 4);
    float* psb   = (float*)carve((size_t)g * 16 * 2048 * 4);
    f16* scb     = (f16*)carve((size_t)g * 16 * 2048 * 2);

    pack_W_T3<<<dim3(16, 16, 3), 256, 0, stream>>>(Wq, Wk, Wv, Wtq);

    const int Mg = g * 2048;
    const dim3 blk(256);
    const dim3 blk512(512);
    const long zSS = (long)2048 * 2048;
    const long zSD = (long)2048 * 1024;

    for (int gi = 0; gi < B / g; ++gi) {
        const float* qg = q + (size_t)gi * Mg * 1024;
        const float* kg = k + (size_t)gi * Mg * 1024;
        float* outq = out + (size_t)gi * Mg * 2048;

        const long nquads = (long)Mg * 256;
        pack_cast_qk<<<dim3((2 * nquads + 255) / 256), blk, 0, stream>>>(
            qg, kg, qpack, kpack, outq, nquads);

        // fused projections: grid.y=3 -> {qp, kp, vpT}
        const dim3 g1((1024 / 256) * (Mg / 256), 3, 1);
        gemm256<CM_PROJ3><<<g1, blk512, 0, stream>>>(
            qpack, Wtq, qp_pack, Mg, 1024, 1024, 1024, 1024, 1024, 0, 0, 0,
            (float*)vpT, nullptr);

        // attnT = kp @ qp^T per z (plain f16, K=1024) -> f16 e + partials
        const dim3 g2((2048 / 256) * (2048 / 256), 1, g);
        gemm256<CM_ATTN><<<g2, blk512, 0, stream>>>(
            kp_pack, qp_pack, attn_w, 2048, 2048, 1024, 1024, 1024, 2048,
            zSD, zSD, zSS, pmb, psb);

        // merge partials -> f16 scale table
        const int nq = g * 2048;
        softmax_merge16<<<dim3((nq + 255) / 256), blk, 0, stream>>>(pmb, psb, scb, nq);

        // context = (e*scale) @ vpT^T -> out cols 1024..2047 (scale in-GEMM)
        float* outg = out + (size_t)gi * Mg * 2048 + 1024;
        const dim3 g3((1024 / 256) * (2048 / 256), 1, g);
        gemm256<CM_PVS><<<g3, blk512, 0, stream>>>(
            attn_w, vpT, outg, 2048, 1024, 2048, 2048, Mg, 2048,
            zSS, 2048, zSS, nullptr, (float*)scb);
    }
}

// Round 15
// 347.931 us; speedup vs baseline: 1.2194x; 1.0381x over previous
//
#include <hip/hip_runtime.h>
#include <hip/hip_bf16.h>

// B=8, S=2048, D=1024, O=1024
// attn = (q Wq)(k Wk)^T = q G k^T, G = Wq Wk^T  (Wk-projection absorbed).
// vp = k@Wv ; w = softmax(attn,-1) ; context = w^T @ vp ;
// out = concat([q, context], -1)  fp32 [B,S,2048]
//
// Pipeline: Gt = Wk_h @ Wq_h^T (8-way K-split + reduce, once);
// qG = qpack @ Gt^T ; vpT = kpack @ Wtv^T (fused grid.y=2);
// attnT = kpack @ qG^T -> f16 e + per-128-row partials; merge -> f16 scales;
// PV multiplies A-frags by scales in-register (CM_PVS).
//
// GEMM: 256x256 tile, BK=64, 8 waves, 32x32x16 f16 MFMA, 2 phases/K-tile,
// counted vmcnt(4), setprio, XCD swizzle, swizzled LDS, launch_bounds(512,2).
// r8-r14 established: schedule variations (barriers, pins, prefetch depth,
// occupancy, interleave placement) do NOT move this structure off ~31% of
// f16 MFMA peak; this round removes work instead (34 GF projection).

typedef __attribute__((ext_vector_type(4))) float f32x4;
typedef __attribute__((ext_vector_type(16))) float f32x16;
typedef _Float16 f16;
typedef __attribute__((ext_vector_type(8))) _Float16 f16x8;
typedef __attribute__((ext_vector_type(4))) _Float16 f16x4;

#define LOG2E 1.4426950408889634f

#define CM_F32     0
#define CM_F16     1
#define CM_F16T    3
#define CM_ATTN    4
#define CM_PROJ2   5
#define CM_PVS     6

#define STAGE(WHICH, KS, KT, BO) do { \
    const char* _gb = (WHICH) ? Bb : Ab; \
    const int _ld = (WHICH) ? ldb : lda; \
    const long _r = (WHICH) ? (long)(bn + srow0) : (long)(bm + srow0); \
    const int _k0 = (KT) * 64 + (KS) * 32 + sh8; \
    char* _dst = (char*)smem + (BO) + (WHICH) * 32768 + (KS) * 16384 + wave * 1024; \
    const char* _g0 = _gb + ((_r * _ld + _k0) << 1); \
    const char* _g1 = _gb + (((_r + 128) * _ld + _k0) << 1); \
    __builtin_amdgcn_global_load_lds((const __attribute__((address_space(1))) void*)_g0, \
        (__attribute__((address_space(3))) void*)_dst, 16, 0, 0); \
    __builtin_amdgcn_global_load_lds((const __attribute__((address_space(1))) void*)_g1, \
        (__attribute__((address_space(3))) void*)(_dst + 8192), 16, 0, 0); \
} while (0)

// One phase: K-half KS, both k-steps. 12 ds_read_b128 (+2 scale if PVS) ->
// [PVS scale-mul] -> barrier -> {STAGE gloads + 16 MFMA} -> VM -> barrier.
#define GPHASE2(KS, STAGE_CODE, VM) do { \
    f16x8 af[2][4], bb[2][2], sv[2]; \
    _Pragma("unroll") \
    for (int s = 0; s < 2; ++s) { \
        _Pragma("unroll") \
        for (int mt = 0; mt < 4; ++mt) \
            af[s][mt] = *(const f16x8*)(smem + \
                ((bufo + (KS) * 16384 + abase[mt]) ^ (s << 5))); \
        _Pragma("unroll") \
        for (int nt = 0; nt < 2; ++nt) \
            bb[s][nt] = *(const f16x8*)(smem + \
                ((bufo + (KS) * 16384 + bbase[nt]) ^ (s << 5))); \
        if (CMODE == CM_PVS) \
            sv[s] = *(const f16x8*)(smem + 131072 + wm * 4096 + \
                t * 128 + (KS) * 64 + s * 32 + (h5 << 4)); \
    } \
    if (CMODE == CM_PVS) { \
        _Pragma("unroll") \
        for (int s = 0; s < 2; ++s) \
            _Pragma("unroll") \
            for (int mt = 0; mt < 4; ++mt) \
                af[s][mt] *= sv[s]; \
    } \
    __builtin_amdgcn_s_barrier(); \
    __builtin_amdgcn_s_setprio(1); \
    STAGE_CODE; \
    _Pragma("unroll") \
    for (int s = 0; s < 2; ++s) \
        _Pragma("unroll") \
        for (int mt = 0; mt < 4; ++mt) \
            _Pragma("unroll") \
            for (int nt = 0; nt < 2; ++nt) \
                acc[mt][nt] = __builtin_amdgcn_mfma_f32_32x32x16_f16( \
                    af[s][mt], bb[s][nt], acc[mt][nt], 0, 0, 0); \
    __builtin_amdgcn_s_setprio(0); \
    VM; \
    __builtin_amdgcn_s_barrier(); \
} while (0)

// CM_PROJ2: blockIdx.y 0 -> qG = A@B^T (f16, ldc=1024); 1 -> vpT via pm
// (A offset M*1024 = kpack; B offset 1M = Wtv). CM_PVS: ps = f16 scale table.
template<int CMODE>
__global__ __launch_bounds__(512, 2)
void gemm256(const f16* __restrict__ A, const f16* __restrict__ B,
             void* __restrict__ Cv,
             int M, int N, int K, int lda, int ldb, int ldc,
             long az, long bz, long cz,
             float* __restrict__ pm, float* __restrict__ ps)
{
    __shared__ __align__(16) char smem[139264];   // 128K buffers + 8K scales

    const int z = blockIdx.z;
    const char* Ab;
    const char* Bb;
    if (CMODE == CM_PROJ2) {
        const int y = blockIdx.y;
        Ab = (const char*)(A + (y ? (long)M * 1024 : 0));
        Bb = (const char*)(B + (long)y * 1024 * 1024);
    } else {
        Ab = (const char*)(A + z * az);
        Bb = (const char*)(B + z * bz);
    }

    // XCD-aware swizzle (all launches have nwg % 8 == 0)
    const int nbx = N >> 8;
    int wg = blockIdx.x;
    const int nwg = gridDim.x;
    if ((nwg & 7) == 0) wg = (wg & 7) * (nwg >> 3) + (wg >> 3);
    const int bm = (wg / nbx) << 8;
    const int bn = (wg % nbx) << 8;

    const int tid = threadIdx.x;
    const int wave = tid >> 6;
    const int lane = tid & 63;
    const int l31 = lane & 31;
    const int h5 = lane >> 5;
    const int wm = wave >> 2;
    const int wn = wave & 3;

    const int f3 = (l31 ^ (l31 >> 2)) & 3;
    const int sl = ((h5 ^ f3) << 4);
    int abase[4], bbase[2];
    #pragma unroll
    for (int mt = 0; mt < 4; ++mt)
        abase[mt] = (wm * 128 + mt * 32 + l31) * 64 + sl;
    #pragma unroll
    for (int nt = 0; nt < 2; ++nt)
        bbase[nt] = 32768 + (wn * 64 + nt * 32 + l31) * 64 + sl;

    const int srow0 = tid >> 2;
    const int sh8 = ((tid ^ (tid >> 2) ^ (tid >> 4)) & 3) * 8;

    f32x16 acc[4][2];
    #pragma unroll
    for (int mt = 0; mt < 4; ++mt)
        #pragma unroll
        for (int nt = 0; nt < 2; ++nt)
            acc[mt][nt] = (f32x16)(0.f);

    const int nt_k = K >> 6;

    {
        if (CMODE == CM_PVS) {
            const char* gsc = (const char*)ps +
                (((long)z * 16 + (bm >> 7)) * 2048) * 2 + tid * 16;
            __builtin_amdgcn_global_load_lds(
                (const __attribute__((address_space(1))) void*)gsc,
                (__attribute__((address_space(3))) void*)
                    ((char*)smem + 131072 + wave * 1024), 16, 0, 0);
        }
        const int t1p = (nt_k > 1) ? 1 : 0;
        STAGE(0, 0, 0, 0);
        STAGE(1, 0, 0, 0);
        STAGE(0, 1, 0, 0);
        STAGE(1, 1, 0, 0);
        STAGE(0, 0, t1p, 65536);
        STAGE(1, 0, t1p, 65536);
        asm volatile("s_waitcnt vmcnt(4)" ::: "memory");
        __builtin_amdgcn_s_barrier();
    }

    for (int t = 0; t < nt_k; ++t) {
        const int bufo = (t & 1) << 16;
        const int nbo = bufo ^ 65536;
        const int t1 = (t + 1 < nt_k) ? t + 1 : nt_k - 1;
        const int t2 = (t + 2 < nt_k) ? t + 2 : nt_k - 1;
        GPHASE2(0, { STAGE(0, 1, t1, nbo); STAGE(1, 1, t1, nbo); }, );
        GPHASE2(1, { STAGE(0, 0, t2, bufo); STAGE(1, 0, t2, bufo); },
                asm volatile("s_waitcnt vmcnt(4)" ::: "memory"));
    }
    asm volatile("s_waitcnt vmcnt(0)" ::: "memory");

    // ---- epilogue: 32x32 D mapping col=lane&31, row=(reg&3)+4*(lane>>5)+8*(reg>>2)
    if (CMODE == CM_ATTN) {
        f16* E = (f16*)Cv + z * cz;
        #pragma unroll
        for (int nt = 0; nt < 2; ++nt) {
            float Mx = -3.4e38f;
            #pragma unroll
            for (int mt = 0; mt < 4; ++mt)
                #pragma unroll
                for (int r = 0; r < 16; ++r)
                    Mx = fmaxf(Mx, acc[mt][nt][r]);
            Mx = fmaxf(Mx, __shfl_xor(Mx, 32, 64));
            float Sm = 0.f;
            #pragma unroll
            for (int mt = 0; mt < 4; ++mt)
                #pragma unroll
                for (int r = 0; r < 16; ++r) {
                    const float e = exp2f((acc[mt][nt][r] - Mx) * LOG2E);
                    acc[mt][nt][r] = e;
                    Sm += e;
                }
            Sm += __shfl_xor(Sm, 32, 64);
            const int col = bn + wn * 64 + nt * 32 + l31;
            #pragma unroll
            for (int mt = 0; mt < 4; ++mt) {
                const int row0 = bm + wm * 128 + mt * 32 + h5 * 4;
                #pragma unroll
                for (int rq = 0; rq < 4; ++rq)
                    #pragma unroll
                    for (int rr = 0; rr < 4; ++rr)
                        E[(long)(row0 + rq * 8 + rr) * ldc + col] =
                            (f16)acc[mt][nt][rq * 4 + rr];
            }
            if (lane < 32) {
                const long pidx = ((long)z * 16 + (bm >> 7) + wm) * N + col;
                pm[pidx] = Mx * LOG2E;
                ps[pidx] = Sm;
            }
        }
        return;
    }

    #pragma unroll
    for (int mt = 0; mt < 4; ++mt) {
        #pragma unroll
        for (int nt = 0; nt < 2; ++nt) {
            const int row0 = bm + wm * 128 + mt * 32 + h5 * 4;
            const int col = bn + wn * 64 + nt * 32 + l31;
            if (CMODE == CM_F32 || CMODE == CM_PVS) {
                float* C = (float*)Cv + z * cz;
                #pragma unroll
                for (int rq = 0; rq < 4; ++rq)
                    #pragma unroll
                    for (int rr = 0; rr < 4; ++rr)
                        C[(long)(row0 + rq * 8 + rr) * ldc + col] =
                            acc[mt][nt][rq * 4 + rr];
            } else if (CMODE == CM_F16) {
                f16* C = (f16*)Cv + z * cz;
                #pragma unroll
                for (int rq = 0; rq < 4; ++rq)
                    #pragma unroll
                    for (int rr = 0; rr < 4; ++rr)
                        C[(long)(row0 + rq * 8 + rr) * ldc + col] =
                            (f16)acc[mt][nt][rq * 4 + rr];
            } else if (CMODE == CM_F16T) {
                f16* C = (f16*)Cv + z * cz;
                #pragma unroll
                for (int rq = 0; rq < 4; ++rq) {
                    f16x4 v;
                    #pragma unroll
                    for (int rr = 0; rr < 4; ++rr) v[rr] = (f16)acc[mt][nt][rq * 4 + rr];
                    *(f16x4*)(C + (long)col * ldc + row0 + rq * 8) = v;
                }
            } else { // CM_PROJ2
                const int y = blockIdx.y;
                if (y == 0) {
                    f16* C = (f16*)Cv;
                    #pragma unroll
                    for (int rq = 0; rq < 4; ++rq)
                        #pragma unroll
                        for (int rr = 0; rr < 4; ++rr)
                            C[(long)(row0 + rq * 8 + rr) * 1024 + col] =
                                (f16)acc[mt][nt][rq * 4 + rr];
                } else {
                    f16* C = (f16*)pm;   // vpT [1024][M]
                    #pragma unroll
                    for (int rq = 0; rq < 4; ++rq) {
                        f16x4 v;
                        #pragma unroll
                        for (int rr = 0; rr < 4; ++rr)
                            v[rr] = (f16)acc[mt][nt][rq * 4 + rr];
                        *(f16x4*)(C + (long)col * M + row0 + rq * 8) = v;
                    }
                }
            }
        }
    }
}

// ---------------------------------------------------------------------------
// fused cast: q rows -> f16 + fp32 copy into out[:,0:1024]; k rows -> f16
// ---------------------------------------------------------------------------
__global__ __launch_bounds__(256)
void pack_cast_qk(const float* __restrict__ qin, const float* __restrict__ kin,
                  f16* __restrict__ qp, f16* __restrict__ kp,
                  float* __restrict__ oq, long nquads)
{
    const long i = (long)blockIdx.x * 256 + threadIdx.x;
    if (i >= 2 * nquads) return;
    const int isK = (i >= nquads);
    const long j = isK ? i - nquads : i;
    const long row = j >> 8;
    const int c = (int)(j & 255) * 4;
    const float4 v = isK ? *(const float4*)(kin + row * 1024 + c)
                         : *(const float4*)(qin + row * 1024 + c);
    f16x4 h;
    h[0] = (f16)v.x; h[1] = (f16)v.y; h[2] = (f16)v.z; h[3] = (f16)v.w;
    if (isK) {
        *(f16x4*)(kp + row * 1024 + c) = h;
    } else {
        *(float4*)(oq + row * 2048 + c) = v;
        *(f16x4*)(qp + row * 1024 + c) = h;
    }
}

// plain fp32 [R,1024] -> f16 [R,1024] cast (row-major, no transpose)
__global__ __launch_bounds__(256)
void cast_f16(const float* __restrict__ in, f16* __restrict__ outp, long nquads)
{
    const long i = (long)blockIdx.x * 256 + threadIdx.x;
    if (i >= nquads) return;
    const long row = i >> 8;
    const int c = (int)(i & 255) * 4;
    const float4 v = *(const float4*)(in + row * 1024 + c);
    f16x4 h;
    h[0] = (f16)v.x; h[1] = (f16)v.y; h[2] = (f16)v.z; h[3] = (f16)v.w;
    *(f16x4*)(outp + row * 1024 + c) = h;
}

// ---------------------------------------------------------------------------
// W [1024 d][1024 o] fp32 -> Wt [1024 o][1024 d] f16 (transpose + cast)
// ---------------------------------------------------------------------------
__global__ __launch_bounds__(256)
void pack_W_T(const float* __restrict__ W, f16* __restrict__ Wt)
{
    __shared__ float tile[64][65];
    const int d0 = blockIdx.y * 64, o0 = blockIdx.x * 64;
    const int t = threadIdx.x;
    const int rr = t >> 4, c4 = (t & 15) * 4;
    #pragma unroll
    for (int it = 0; it < 4; ++it) {
        const int r = rr + it * 16;
        const float4 v = *(const float4*)(W + (long)(d0 + r) * 1024 + o0 + c4);
        tile[r][c4] = v.x; tile[r][c4 + 1] = v.y;
        tile[r][c4 + 2] = v.z; tile[r][c4 + 3] = v.w;
    }
    __syncthreads();
    #pragma unroll
    for (int it = 0; it < 4; ++it) {
        const int orow = rr + it * 16;
        f16x4 h;
        #pragma unroll
        for (int j = 0; j < 4; ++j) h[j] = (f16)tile[c4 + j][orow];
        *(f16x4*)(Wt + (long)(o0 + orow) * 1024 + d0 + c4) = h;
    }
}

// ---------------------------------------------------------------------------
// reduce 8 f32 partials [8][1024*1024] -> f16 Gt[1024*1024]
// ---------------------------------------------------------------------------
__global__ __launch_bounds__(256)
void gt_reduce(const float* __restrict__ P, f16* __restrict__ Gt, long nquads)
{
    const long i = (long)blockIdx.x * 256 + threadIdx.x;
    if (i >= nquads) return;
    float4 s = *(const float4*)(P + i * 4);
    #pragma unroll
    for (int z = 1; z < 8; ++z) {
        const float4 v = *(const float4*)(P + (long)z * 1048576 + i * 4);
        s.x += v.x; s.y += v.y; s.z += v.z; s.w += v.w;
    }
    f16x4 h;
    h[0] = (f16)s.x; h[1] = (f16)s.y; h[2] = (f16)s.z; h[3] = (f16)s.w;
    *(f16x4*)(Gt + i * 4) = h;
}

// ---------------------------------------------------------------------------
// merge 16 per-block partials -> f16 scale[z][16][2048] = exp2(pm - L)
// ---------------------------------------------------------------------------
__global__ __launch_bounds__(256)
void softmax_merge16(const float* __restrict__ pm, const float* __restrict__ ps,
                     f16* __restrict__ scale, int nq)
{
    const int idx = blockIdx.x * 256 + threadIdx.x;
    if (idx >= nq) return;
    const int z = idx >> 11, q = idx & 2047;
    const float* pmz = pm + ((long)z * 16) * 2048 + q;
    const float* psz = ps + ((long)z * 16) * 2048 + q;
    float mx = -3.4e38f;
    #pragma unroll
    for (int j = 0; j < 16; ++j) mx = fmaxf(mx, pmz[j * 2048]);
    float s = 0.f;
    #pragma unroll
    for (int j = 0; j < 16; ++j)
        s += psz[j * 2048] * exp2f(pmz[j * 2048] - mx);
    const float L = mx + log2f(s);
    f16* sc = scale + ((long)z * 16) * 2048 + q;
    #pragma unroll
    for (int j = 0; j < 16; ++j)
        sc[j * 2048] = (f16)exp2f(pmz[j * 2048] - L);
}

// ---------------------------------------------------------------------------
__global__ __launch_bounds__(256)
void copy_q_kernel(const float* __restrict__ q, float* __restrict__ out, long n4)
{
    const long idx = (long)blockIdx.x * 256 + threadIdx.x;
    if (idx >= n4) return;
    const long row = idx >> 8;
    const long c4 = idx & 255;
    *(float4*)(&out[row * 2048 + c4 * 4]) =
        *(const float4*)(&q[row * 1024 + c4 * 4]);
}

// ===========================================================================
// fp32 fallback for small workspaces
// ===========================================================================
#define BM 64
#define BN 64
#define BKF 16
template<int opA, int opB>
__global__ __launch_bounds__(256)
void sgemm(const float* __restrict__ A, const float* __restrict__ B,
           float* __restrict__ C,
           int M, int N, int K, int lda, int ldb, int ldc)
{
    __shared__ float As[BKF][BM];
    __shared__ float Bs[BKF][BN];
    const int tid = threadIdx.x;
    const int tx = tid & 15, ty = tid >> 4;
    const int bm = blockIdx.y * BM, bn = blockIdx.x * BN;
    float acc[4][4] = {};
    for (int k0 = 0; k0 < K; k0 += BKF) {
        if (opA == 0) {
            const int row = tid >> 2, kq = (tid & 3) * 4;
            const float4 v = *(const float4*)(A + (long)(bm + row) * lda + (k0 + kq));
            As[kq + 0][row] = v.x; As[kq + 1][row] = v.y;
            As[kq + 2][row] = v.z; As[kq + 3][row] = v.w;
        } else {
            const int kk = tid >> 4, mq = (tid & 15) * 4;
            *(float4*)(&As[kk][mq]) =
                *(const float4*)(A + (long)(k0 + kk) * lda + (bm + mq));
        }
        if (opB == 0) {
            const int kk = tid >> 4, nq = (tid & 15) * 4;
            *(float4*)(&Bs[kk][nq]) =
                *(const float4*)(B + (long)(k0 + kk) * ldb + (bn + nq));
        } else {
            const int row = tid >> 2, kq = (tid & 3) * 4;
            const float4 v = *(const float4*)(B + (long)(bn + row) * ldb + (k0 + kq));
            Bs[kq + 0][row] = v.x; Bs[kq + 1][row] = v.y;
            Bs[kq + 2][row] = v.z; Bs[kq + 3][row] = v.w;
        }
        __syncthreads();
        #pragma unroll
        for (int kk = 0; kk < BKF; ++kk) {
            const float4 a = *(const float4*)(&As[kk][ty * 4]);
            const float4 b = *(const float4*)(&Bs[kk][tx * 4]);
            const float av[4] = {a.x, a.y, a.z, a.w};
            const float bv[4] = {b.x, b.y, b.z, b.w};
            #pragma unroll
            for (int i = 0; i < 4; ++i)
                #pragma unroll
                for (int j = 0; j < 4; ++j)
                    acc[i][j] += av[i] * bv[j];
        }
        __syncthreads();
    }
    #pragma unroll
    for (int i = 0; i < 4; ++i) {
        const float4 v = make_float4(acc[i][0], acc[i][1], acc[i][2], acc[i][3]);
        *(float4*)(&C[(long)(bm + ty * 4 + i) * ldc + (bn + tx * 4)]) = v;
    }
}

__device__ __forceinline__ float wave_reduce_max(float v) {
    #pragma unroll
    for (int off = 1; off < 64; off <<= 1)
        v = fmaxf(v, __shfl_xor(v, off, 64));
    return v;
}
__device__ __forceinline__ float wave_reduce_sum(float v) {
    #pragma unroll
    for (int off = 1; off < 64; off <<= 1)
        v += __shfl_xor(v, off, 64);
    return v;
}

__global__ __launch_bounds__(256)
void softmax_rows2048(float* __restrict__ X)
{
    float* x = X + (long)blockIdx.x * 2048;
    const int tid = threadIdx.x;
    float4 v0 = *(const float4*)(&x[tid * 4]);
    float4 v1 = *(const float4*)(&x[1024 + tid * 4]);
    float m = fmaxf(fmaxf(fmaxf(v0.x, v0.y), fmaxf(v0.z, v0.w)),
                    fmaxf(fmaxf(v1.x, v1.y), fmaxf(v1.z, v1.w)));
    m = wave_reduce_max(m);
    __shared__ float sm[4];
    __shared__ float ss[4];
    const int wid = tid >> 6;
    if ((tid & 63) == 0) sm[wid] = m;
    __syncthreads();
    m = fmaxf(fmaxf(sm[0], sm[1]), fmaxf(sm[2], sm[3]));
    v0.x = expf(v0.x - m); v0.y = expf(v0.y - m);
    v0.z = expf(v0.z - m); v0.w = expf(v0.w - m);
    v1.x = expf(v1.x - m); v1.y = expf(v1.y - m);
    v1.z = expf(v1.z - m); v1.w = expf(v1.w - m);
    float s = (v0.x + v0.y + v0.z + v0.w) + (v1.x + v1.y + v1.z + v1.w);
    s = wave_reduce_sum(s);
    if ((tid & 63) == 0) ss[wid] = s;
    __syncthreads();
    s = ss[0] + ss[1] + ss[2] + ss[3];
    const float inv = 1.0f / s;
    v0.x *= inv; v0.y *= inv; v0.z *= inv; v0.w *= inv;
    v1.x *= inv; v1.y *= inv; v1.z *= inv; v1.w *= inv;
    *(float4*)(&x[tid * 4]) = v0;
    *(float4*)(&x[1024 + tid * 4]) = v1;
}

static void fallback_fp32(const float* q, const float* k, const float* Wq,
                          const float* Wk, const float* Wv, float* out,
                          void* d_ws, hipStream_t stream)
{
    const int S = 2048, D = 1024, O = 1024, B = 8;
    float* qp = (float*)d_ws;
    float* kp = qp + (size_t)S * O;
    float* vp = kp + (size_t)S * O;
    float* attn = vp + (size_t)S * O;
    const long n4 = (long)B * S * D / 4;
    copy_q_kernel<<<dim3((n4 + 255) / 256), 256, 0, stream>>>(q, out, n4);
    const dim3 blk(256);
    const dim3 gproj(O / BN, S / BM), gattn(S / BN, S / BM), gctx(O / BN, S / BM);
    for (int b = 0; b < B; ++b) {
        const float* qb = q + (size_t)b * S * D;
        const float* kb = k + (size_t)b * S * D;
        float* outc = out + (size_t)b * S * 2048 + D;
        sgemm<0, 0><<<gproj, blk, 0, stream>>>(qb, Wq, qp, S, O, D, D, O, O);
        sgemm<0, 0><<<gproj, blk, 0, stream>>>(kb, Wk, kp, S, O, D, D, O, O);
        sgemm<0, 0><<<gproj, blk, 0, stream>>>(kb, Wv, vp, S, O, D, D, O, O);
        sgemm<0, 1><<<gattn, blk, 0, stream>>>(qp, kp, attn, S, S, O, O, O, S);
        softmax_rows2048<<<dim3(S), blk, 0, stream>>>(attn);
        sgemm<1, 0><<<gctx, blk, 0, stream>>>(attn, vp, outc, S, O, S, S, O, 2048);
    }
}

// ===========================================================================
extern "C" void kernel_launch(void* const* d_in, const int* in_sizes, int n_in,
                              void* d_out, int out_size, void* d_ws, size_t ws_size,
                              hipStream_t stream)
{
    const float* q  = (const float*)d_in[0];
    const float* k  = (const float*)d_in[1];
    const float* Wq = (const float*)d_in[2];
    const float* Wk = (const float*)d_in[3];
    const float* Wv = (const float*)d_in[4];
    float* out = (float*)d_out;

    const int B = 8, S = 2048;

    auto need = [](int g) -> size_t {
        const size_t fixed = ((size_t)1024 * 1024 * 2) * 4      // Gt,Wtv,Wq_h,Wk_h
                           + (size_t)8 * 1024 * 1024 * 4;       // Gt partials
        const size_t pkA = (size_t)g * 2048 * 1024 * 2;         // qpack,kpack,qG
        const size_t vpT = (size_t)1024 * g * 2048 * 2;
        const size_t aw  = (size_t)g * 2048 * 2048 * 2;
        const size_t pp  = 2 * (size_t)g * 16 * 2048 * 4 + (size_t)g * 16 * 2048 * 2;
        return fixed + 3 * pkA + vpT + aw + pp + 32 * 256;
    };
    int g = 0;
    for (int cand : {8, 4, 2, 1})
        if (need(cand) <= ws_size) { g = cand; break; }
    if (g == 0) { fallback_fp32(q, k, Wq, Wk, Wv, out, d_ws, stream); return; }

    char* p = (char*)d_ws;
    auto carve = [&](size_t bytes) {
        char* r = p;
        p += (bytes + 255) & ~(size_t)255;
        return r;
    };
    // NOTE: Gt & Wtv contiguous (B-trio for CM_PROJ2); qpack & kpack
    // contiguous (A-trio). 1024*1024*2 bytes = 2 MiB is 256-aligned.
    f16* Gt   = (f16*)carve((size_t)1024 * 1024 * 2);
    f16* Wtv  = (f16*)carve((size_t)1024 * 1024 * 2);
    f16* Wq_h = (f16*)carve((size_t)1024 * 1024 * 2);
    f16* Wk_h = (f16*)carve((size_t)1024 * 1024 * 2);
    float* Gp = (float*)carve((size_t)8 * 1024 * 1024 * 4);
    const size_t pkAB = (size_t)g * 2048 * 1024 * 2;
    f16* qpack  = (f16*)carve(pkAB);
    f16* kpack  = (f16*)carve(pkAB);
    f16* qG     = (f16*)carve(pkAB);
    f16* vpT    = (f16*)carve((size_t)1024 * g * 2048 * 2);
    f16* attn_w = (f16*)carve((size_t)g * 2048 * 2048 * 2);
    float* pmb  = (float*)carve((size_t)g * 16 * 2048 * 4);
    float* psb  = (float*)carve((size_t)g * 16 * 2048 * 4);
    f16* scb    = (f16*)carve((size_t)g * 16 * 2048 * 2);

    const dim3 blk(256);
    const dim3 blk512(512);

    // --- once: Wv transpose, Wq/Wk casts, Gt = Wk_h @ Wq_h^T (8-way K-split)
    pack_W_T<<<dim3(16, 16), blk, 0, stream>>>(Wv, Wtv);
    cast_f16<<<dim3(1024), blk, 0, stream>>>(Wq, Wq_h, 1024 * 256);
    cast_f16<<<dim3(1024), blk, 0, stream>>>(Wk, Wk_h, 1024 * 256);
    gemm256<CM_F32><<<dim3(16, 1, 8), blk512, 0, stream>>>(
        Wk_h, Wq_h, Gp, 1024, 1024, 128, 1024, 1024, 1024,
        128, 128, (long)1024 * 1024, nullptr, nullptr);
    gt_reduce<<<dim3(1024), blk, 0, stream>>>(Gp, Gt, 1024 * 256);

    const int Mg = g * 2048;
    const long zSS = (long)2048 * 2048;
    const long zSD = (long)2048 * 1024;

    for (int gi = 0; gi < B / g; ++gi) {
        const float* qg = q + (size_t)gi * Mg * 1024;
        const float* kg = k + (size_t)gi * Mg * 1024;
        float* outq = out + (size_t)gi * Mg * 2048;

        const long nquads = (long)Mg * 256;
        pack_cast_qk<<<dim3((2 * nquads + 255) / 256), blk, 0, stream>>>(
            qg, kg, qpack, kpack, outq, nquads);

        // fused projections: y=0 -> qG = qpack@Gt^T ; y=1 -> vpT = kpack@Wtv^T
        const dim3 g1((1024 / 256) * (Mg / 256), 2, 1);
        gemm256<CM_PROJ2><<<g1, blk512, 0, stream>>>(
            qpack, Gt, qG, Mg, 1024, 1024, 1024, 1024, 1024, 0, 0, 0,
            (float*)vpT, nullptr);

        // attnT = kpack @ qG^T per z -> f16 e + partials
        const dim3 g2((2048 / 256) * (2048 / 256), 1, g);
        gemm256<CM_ATTN><<<g2, blk512, 0, stream>>>(
            kpack, qG, attn_w, 2048, 2048, 1024, 1024, 1024, 2048,
            zSD, zSD, zSS, pmb, psb);

        // merge partials -> f16 scale table
        const int nq = g * 2048;
        softmax_merge16<<<dim3((nq + 255) / 256), blk, 0, stream>>>(pmb, psb, scb, nq);

        // context = (e*scale) @ vpT^T -> out cols 1024..2047
        float* outg = out + (size_t)gi * Mg * 2048 + 1024;
        const dim3 g3((1024 / 256) * (2048 / 256), 1, g);
        gemm256<CM_PVS><<<g3, blk512, 0, stream>>>(
            attn_w, vpT, outg, 2048, 1024, 2048, 2048, Mg, 2048,
            zSS, 2048, zSS, nullptr, (float*)scb);
    }
}